// Round 8
// baseline (186.048 us; speedup 1.0000x reference)
//
#include <hip/hip_runtime.h>
#include <math.h>

// Problem constants (B,C,H,W = 32,512,56,56; top_t = round(3136*0.1) = 314)
#define NB 32
#define NC 512
#define NH 56
#define NW 56
#define NHW 3136
#define TOPT 314
#define NR 32
#define RBUCK 2048
#define HWORDS 2112                       // permuted table: max index 2103
#define HPERM(b) (((b) >> 3) + 264u * ((b) & 7u))

typedef float f32x4 __attribute__((ext_vector_type(4)));

__device__ __forceinline__ unsigned int f2s(float f) {
    unsigned int b = __float_as_uint(f);
    return (b & 0x80000000u) ? ~b : (b | 0x80000000u);
}
__device__ __forceinline__ float s2f(unsigned int u) {
    unsigned int b = (u & 0x80000000u) ? (u ^ 0x80000000u) : ~u;
    return __uint_as_float(b);
}

// ---------------- Kernel 1: exact top-314 sum + max, TWO rows/block ------
// R5 SWAR structure (2 rows/block, packed 16-bit counts) plus:
//  (a) quantile-pruned round 0: per-row mu,sigma in registers, probe
//      B = bucket_align(f2s(mu+1.1*sigma)); a VALU count pass verifies
//      >= 314 survivors (else B=0 exact fallback); round-0 histograms
//      only u >= B  (~13% of elements -> ~7x fewer LDS atomics and far
//      fewer same-value collisions). Exact: B bucket-aligned means t's
//      bucket contains only survivors.
//  (b) bank-permuted histogram word(b) = (b>>3) + 264*(b&7): fold reads
//      are lane-stride-1 (was 16-way conflicted); adjacent hot buckets
//      sit 8 banks apart for the atomic phase.
__global__ __launch_bounds__(256) void topk_pool_kernel(
        const float* __restrict__ x,
        float* __restrict__ pool_avg, float* __restrict__ pool_max) {
    __shared__ unsigned int hist[2][HWORDS];     // 16.5 KB
    __shared__ unsigned int wtot[4];
    __shared__ unsigned int sh_pref[2], sh_k[2];
    __shared__ float shst[4][4];                 // per-wave sA,qA,sB,qB
    __shared__ unsigned int shc[4];              // per-wave packed counts
    __shared__ float redsA[4], redsB[4];
    __shared__ unsigned int redmA[4], redmB[4];

    const int rowA = blockIdx.x * 2;
    const int tid = threadIdx.x;
    const int wid = tid >> 6;
    const int lane = tid & 63;
    const float* xa = x + (size_t)rowA * NHW;
    const float* xb = xa + NHW;
    const float4* xa4 = (const float4*)xa;
    const float4* xb4 = (const float4*)xb;

    // 3136 = 12*256 + 64: three float4 loads + one scalar (tid<64), per row
    float4 a0 = xa4[tid], a1 = xa4[256 + tid], a2 = xa4[512 + tid];
    float4 b0 = xb4[tid], b1 = xb4[256 + tid], b2 = xb4[512 + tid];
    const bool has13 = (tid < 64);
    float exA = has13 ? xa[3072 + tid] : 0.f;    // 0 contributes nothing to stats
    float exB = has13 ? xb[3072 + tid] : 0.f;

    // ---- per-row mean/var estimate (registers + shfl) ----
    float sA = 0.f, qA = 0.f, sB = 0.f, qB = 0.f;
#define ACCA(v) { sA += (v); qA = fmaf((v), (v), qA); }
#define ACCB(v) { sB += (v); qB = fmaf((v), (v), qB); }
    ACCA(a0.x) ACCA(a0.y) ACCA(a0.z) ACCA(a0.w)
    ACCA(a1.x) ACCA(a1.y) ACCA(a1.z) ACCA(a1.w)
    ACCA(a2.x) ACCA(a2.y) ACCA(a2.z) ACCA(a2.w) ACCA(exA)
    ACCB(b0.x) ACCB(b0.y) ACCB(b0.z) ACCB(b0.w)
    ACCB(b1.x) ACCB(b1.y) ACCB(b1.z) ACCB(b1.w)
    ACCB(b2.x) ACCB(b2.y) ACCB(b2.z) ACCB(b2.w) ACCB(exB)
#undef ACCA
#undef ACCB

    unsigned int u[13], w[13];
    u[0] = f2s(a0.x); u[1] = f2s(a0.y); u[2]  = f2s(a0.z); u[3]  = f2s(a0.w);
    u[4] = f2s(a1.x); u[5] = f2s(a1.y); u[6]  = f2s(a1.z); u[7]  = f2s(a1.w);
    u[8] = f2s(a2.x); u[9] = f2s(a2.y); u[10] = f2s(a2.z); u[11] = f2s(a2.w);
    u[12] = f2s(exA);
    w[0] = f2s(b0.x); w[1] = f2s(b0.y); w[2]  = f2s(b0.z); w[3]  = f2s(b0.w);
    w[4] = f2s(b1.x); w[5] = f2s(b1.y); w[6]  = f2s(b1.z); w[7]  = f2s(b1.w);
    w[8] = f2s(b2.x); w[9] = f2s(b2.y); w[10] = f2s(b2.z); w[11] = f2s(b2.w);
    w[12] = f2s(exB);

    #pragma unroll
    for (int off = 32; off > 0; off >>= 1) {
        sA += __shfl_down(sA, off); qA += __shfl_down(qA, off);
        sB += __shfl_down(sB, off); qB += __shfl_down(qB, off);
    }
    if (lane == 0) { shst[wid][0] = sA; shst[wid][1] = qA;
                     shst[wid][2] = sB; shst[wid][3] = qB; }
    __syncthreads();
    const float inv_n = 1.0f / (float)NHW;
    float SAt = shst[0][0] + shst[1][0] + shst[2][0] + shst[3][0];
    float QAt = shst[0][1] + shst[1][1] + shst[2][1] + shst[3][1];
    float SBt = shst[0][2] + shst[1][2] + shst[2][2] + shst[3][2];
    float QBt = shst[0][3] + shst[1][3] + shst[2][3] + shst[3][3];
    const float muA = SAt * inv_n, muB = SBt * inv_n;
    const float sgA = sqrtf(fmaxf(QAt * inv_n - muA * muA, 0.f));
    const float sgB = sqrtf(fmaxf(QBt * inv_n - muB * muB, 0.f));
    unsigned int BA = f2s(fmaf(1.1f, sgA, muA)) & 0xFFE00000u;   // bucket-aligned
    unsigned int BB = f2s(fmaf(1.1f, sgB, muB)) & 0xFFE00000u;

    // ---- survivor count (VALU only) + fallback decision ----
    unsigned int cnt = 0u;
    #pragma unroll
    for (int j = 0; j < 13; ++j) {
        const bool live = (j < 12) || has13;
        if (live) {
            cnt += (u[j] >= BA) ? 1u : 0u;
            cnt += (w[j] >= BB) ? 65536u : 0u;
        }
    }
    #pragma unroll
    for (int off = 32; off > 0; off >>= 1) cnt += __shfl_down(cnt, off);
    if (lane == 0) shc[wid] = cnt;
    __syncthreads();
    const unsigned int ctot = shc[0] + shc[1] + shc[2] + shc[3];
    if ((ctot & 0xFFFFu) < TOPT) BA = 0u;        // exact fallback (rare)
    if ((ctot >> 16) < TOPT) BB = 0u;

    unsigned int prefA = 0u, prefB = 0u, mask = 0u;
    unsigned int kA = TOPT, kB = TOPT;
    const int shifts[3] = {21, 10, 0};
    #pragma unroll
    for (int r = 0; r < 3; ++r) {
        const int shift = shifts[r];
        {   // zero histogram(s): HWORDS*2/4 = 1056 uint4
            uint4 z = make_uint4(0u, 0u, 0u, 0u);
            uint4* h0 = (uint4*)hist[0];
            h0[tid] = z; h0[256 + tid] = z;
            if (r == 0) {
                h0[512 + tid] = z; h0[768 + tid] = z;
                if (tid < 32) h0[1024 + tid] = z;
            } else if (tid < 16) {
                h0[512 + tid] = z;
            }
        }
        __syncthreads();
        unsigned int* h = (r == 0) ? hist[wid >> 1] : hist[0];
        if (r == 0) {
            #pragma unroll
            for (int j = 0; j < 13; ++j) {
                const bool live = (j < 12) || has13;
                if (live && (u[j] >= BA))
                    atomicAdd(&h[HPERM((u[j] >> 21))], 1u);
                if (live && (w[j] >= BB))
                    atomicAdd(&h[HPERM((w[j] >> 21))], 65536u);
            }
        } else {
            #pragma unroll
            for (int j = 0; j < 13; ++j) {
                const bool live = (j < 12) || has13;
                if (live && ((u[j] & mask) == prefA))
                    atomicAdd(&h[HPERM(((u[j] >> shift) & (RBUCK - 1u)))], 1u);
                if (live && ((w[j] & mask) == prefB))
                    atomicAdd(&h[HPERM(((w[j] >> shift) & (RBUCK - 1u)))], 65536u);
            }
        }
        __syncthreads();

        // fold 8 buckets/thread (bucket 8*tid+bb at word tid+264*bb):
        // lane-stride-1 reads, conflict-free
        unsigned int vv[8];
        unsigned int g = 0u;
        if (r == 0) {
            #pragma unroll
            for (int bb = 0; bb < 8; ++bb) {
                vv[bb] = hist[0][tid + 264 * bb] + hist[1][tid + 264 * bb];
                g += vv[bb];
            }
        } else {
            #pragma unroll
            for (int bb = 0; bb < 8; ++bb) { vv[bb] = hist[0][tid + 264 * bb]; g += vv[bb]; }
        }
        // packed suffix-inclusive scan over threads
        unsigned int S = g;
        #pragma unroll
        for (int off = 1; off < 64; off <<= 1) {
            unsigned int t2 = __shfl_down(S, off);
            if (lane + off < 64) S += t2;
        }
        if (lane == 0) wtot[wid] = S;
        __syncthreads();
        unsigned int hi = 0u;
        if (wid < 3) hi += wtot[wid + 1];
        if (wid < 2) hi += wtot[wid + 2];
        if (wid < 1) hi += wtot[wid + 3];
        S += hi;                               // packed: count in buckets >= mine
        const unsigned int SloT = S & 0xFFFFu, ShiT = S >> 16;
        const unsigned int gLo = g & 0xFFFFu,  gHi = g >> 16;
        const unsigned int aboveLo = SloT - gLo, aboveHi = ShiT - gHi;
        if (SloT >= kA && aboveLo < kA) {      // unique crossing thread, row A
            unsigned int cum = aboveLo;
            #pragma unroll
            for (int bb = 7; bb >= 0; --bb) {
                const unsigned int hh = vv[bb] & 0xFFFFu;
                if (cum + hh >= kA) {
                    sh_pref[0] = prefA | ((unsigned int)(8 * tid + bb) << shift);
                    sh_k[0] = kA - cum;
                    break;
                }
                cum += hh;
            }
        }
        if (ShiT >= kB && aboveHi < kB) {      // row B
            unsigned int cum = aboveHi;
            #pragma unroll
            for (int bb = 7; bb >= 0; --bb) {
                const unsigned int hh = vv[bb] >> 16;
                if (cum + hh >= kB) {
                    sh_pref[1] = prefB | ((unsigned int)(8 * tid + bb) << shift);
                    sh_k[1] = kB - cum;
                    break;
                }
                cum += hh;
            }
        }
        __syncthreads();
        prefA = sh_pref[0]; kA = sh_k[0];
        prefB = sh_pref[1]; kB = sh_k[1];
        mask = 0xFFFFFFFFu << shift;
    }

    // ---- final: per-row sum of elements > t (+ k ties), and row max ----
    const unsigned int tA = prefA, tB = prefB;
    float sumA = 0.f, sumB = 0.f;
    unsigned int mA = 0u, mB = 0u;
    #pragma unroll
    for (int j = 0; j < 13; ++j) {
        const bool live = (j < 12) || has13;
        if (live) {
            mA = max(mA, u[j]);
            if (u[j] > tA) sumA += s2f(u[j]);
            mB = max(mB, w[j]);
            if (w[j] > tB) sumB += s2f(w[j]);
        }
    }
    #pragma unroll
    for (int off = 32; off > 0; off >>= 1) {
        sumA += __shfl_down(sumA, off);
        sumB += __shfl_down(sumB, off);
        mA = max(mA, __shfl_down(mA, off));
        mB = max(mB, __shfl_down(mB, off));
    }
    if (lane == 0) { redsA[wid] = sumA; redsB[wid] = sumB;
                     redmA[wid] = mA;   redmB[wid] = mB; }
    __syncthreads();
    if (tid == 0) {
        float totA = redsA[0] + redsA[1] + redsA[2] + redsA[3] + (float)kA * s2f(tA);
        float totB = redsB[0] + redsB[1] + redsB[2] + redsB[3] + (float)kB * s2f(tB);
        pool_avg[rowA]     = totA * (1.0f / (float)TOPT);
        pool_avg[rowA + 1] = totB * (1.0f / (float)TOPT);
        pool_max[rowA]     = s2f(max(max(redmA[0], redmA[1]), max(redmA[2], redmA[3])));
        pool_max[rowA + 1] = s2f(max(max(redmB[0], redmB[1]), max(redmB[2], redmB[3])));
    }
}

// ---------------- Kernel 2: channel-MLP + sigmoid -> s[b,c] --------------
__global__ __launch_bounds__(256) void mlp_kernel(
        const float* __restrict__ pool_avg, const float* __restrict__ pool_max,
        const float* __restrict__ w1, const float* __restrict__ b1,
        const float* __restrict__ w2, const float* __restrict__ b2,
        float* __restrict__ s_out) {
    __shared__ float pa[NC], pm[NC], h1a[NR], h1m[NR];
    const int b = blockIdx.x, tid = threadIdx.x;
    for (int c = tid; c < NC; c += 256) {
        pa[c] = pool_avg[b * NC + c];
        pm[c] = pool_max[b * NC + c];
    }
    __syncthreads();
    if (tid < 64) {
        const int r = tid & 31;
        const float* wrow = w1 + r * NC;
        const float* p = (tid < 32) ? pa : pm;
        float acc = b1[r];
        for (int c = 0; c < NC; ++c) acc += p[c] * wrow[c];
        float h = fmaxf(acc, 0.f);
        if (tid < 32) h1a[r] = h; else h1m[r] = h;
    }
    __syncthreads();
    for (int c = tid; c < NC; c += 256) {
        float acc = 2.f * b2[c];
        const float* wrow = w2 + c * NR;
        for (int r = 0; r < NR; ++r) acc += (h1a[r] + h1m[r]) * wrow[r];
        s_out[b * NC + c] = 1.f / (1.f + expf(-acc));
    }
}

// ---------------- Kernel 3: channel max/mean of x*s -> cp ----------------
__global__ __launch_bounds__(256) void spatial_pool_kernel(
        const float* __restrict__ x, const float* __restrict__ s,
        float* __restrict__ cp_max, float* __restrict__ cp_avg) {
    __shared__ float sc[NC];
    __shared__ float4 pmx[7][32];
    __shared__ float4 psm[7][32];
    const int b = blockIdx.y, tid = threadIdx.x;
    const int qo = tid & 31;                 // float4-pixel within tile
    const int cg = tid >> 5;                 // channel group 0..7
    const int q = blockIdx.x * 32 + qo;      // float4 index, 0..783 valid
    for (int c = tid; c < NC; c += 256) sc[c] = s[b * NC + c];
    __syncthreads();
    const float4* xb4 = (const float4*)(x + (size_t)b * NC * NHW);
    float4 mx = make_float4(-INFINITY, -INFINITY, -INFINITY, -INFINITY);
    float4 sm = make_float4(0.f, 0.f, 0.f, 0.f);
    const bool valid = (q < NHW / 4);
    if (valid) {
        #pragma unroll 2
        for (int c = cg * 64; c < cg * 64 + 64; ++c) {
            float4 v = xb4[(size_t)c * (NHW / 4) + q];
            const float scv = sc[c];
            v.x *= scv; v.y *= scv; v.z *= scv; v.w *= scv;
            mx.x = fmaxf(mx.x, v.x); mx.y = fmaxf(mx.y, v.y);
            mx.z = fmaxf(mx.z, v.z); mx.w = fmaxf(mx.w, v.w);
            sm.x += v.x; sm.y += v.y; sm.z += v.z; sm.w += v.w;
        }
    }
    if (cg > 0 && valid) { pmx[cg - 1][qo] = mx; psm[cg - 1][qo] = sm; }
    __syncthreads();
    if (cg == 0 && valid) {
        #pragma unroll
        for (int i = 0; i < 7; ++i) {
            const float4 m2 = pmx[i][qo];
            const float4 s2 = psm[i][qo];
            mx.x = fmaxf(mx.x, m2.x); mx.y = fmaxf(mx.y, m2.y);
            mx.z = fmaxf(mx.z, m2.z); mx.w = fmaxf(mx.w, m2.w);
            sm.x += s2.x; sm.y += s2.y; sm.z += s2.z; sm.w += s2.w;
        }
        const float inv = 1.0f / (float)NC;
        sm.x *= inv; sm.y *= inv; sm.z *= inv; sm.w *= inv;
        ((float4*)(cp_max + b * NHW))[q] = mx;
        ((float4*)(cp_avg + b * NHW))[q] = sm;
    }
}

// ---------------- Kernel 4: 7x7 conv + BN + sigmoid -> g[b,hw] -----------
__global__ __launch_bounds__(256) void conv_gate_kernel(
        const float* __restrict__ cp_max, const float* __restrict__ cp_avg,
        const float* __restrict__ conv_w,
        const float* __restrict__ gamma, const float* __restrict__ beta,
        const float* __restrict__ mean, const float* __restrict__ var,
        float* __restrict__ g) {
    __shared__ float wgt[98];
    const int b = blockIdx.y, tid = threadIdx.x;
    const int p = blockIdx.x * 256 + tid;
    if (tid < 98) wgt[tid] = conv_w[tid];
    __syncthreads();
    if (p >= NHW) return;
    const int h = p / NW, w = p - h * NW;
    const float* cm = cp_max + b * NHW;
    const float* ca = cp_avg + b * NHW;
    float acc = 0.f;
    for (int i = 0; i < 7; ++i) {
        const int hh = h - 3 + i;
        if (hh < 0 || hh >= NH) continue;
        for (int j = 0; j < 7; ++j) {
            const int ww = w - 3 + j;
            if (ww < 0 || ww >= NW) continue;
            const int q = hh * NW + ww;
            acc += cm[q] * wgt[i * 7 + j] + ca[q] * wgt[49 + i * 7 + j];
        }
    }
    const float bnv = (acc - mean[0]) * rsqrtf(var[0] + 1e-5f) * gamma[0] + beta[0];
    g[b * NHW + p] = 1.f / (1.f + expf(-bnv));
}

// ---------------- Kernel 5: out = x * s[b,c] * g[b,hw] -------------------
__global__ __launch_bounds__(256) void scale_out_kernel(
        const float* __restrict__ x, const float* __restrict__ s,
        const float* __restrict__ g, float* __restrict__ out) {
    const int bc = blockIdx.x;               // 0..16383
    const int b = bc >> 9;
    const int tid = threadIdx.x;
    const float sv = s[bc];
    const f32x4* xr = (const f32x4*)(x + (size_t)bc * NHW);
    const f32x4* gr = (const f32x4*)(g + (size_t)b * NHW);
    f32x4* orow = (f32x4*)(out + (size_t)bc * NHW);
    #pragma unroll
    for (int i = 0; i < 3; ++i) {            // 3*256 = 768 of 784 float4s
        const int q = tid + 256 * i;
        f32x4 xv = xr[q];
        f32x4 gv = gr[q];
        f32x4 ov = xv * sv * gv;
        __builtin_nontemporal_store(ov, &orow[q]);
    }
    if (tid < 16) {                          // tail: 768..783
        const int q = 768 + tid;
        f32x4 xv = xr[q];
        f32x4 gv = gr[q];
        f32x4 ov = xv * sv * gv;
        __builtin_nontemporal_store(ov, &orow[q]);
    }
}

extern "C" void kernel_launch(void* const* d_in, const int* in_sizes, int n_in,
                              void* d_out, int out_size, void* d_ws, size_t ws_size,
                              hipStream_t stream) {
    const float* x      = (const float*)d_in[0];
    const float* w1     = (const float*)d_in[1];
    const float* b1     = (const float*)d_in[2];
    const float* w2     = (const float*)d_in[3];
    const float* b2     = (const float*)d_in[4];
    const float* conv_w = (const float*)d_in[5];
    const float* gamma  = (const float*)d_in[6];
    const float* beta   = (const float*)d_in[7];
    const float* mean   = (const float*)d_in[8];
    const float* var    = (const float*)d_in[9];
    float* out = (float*)d_out;

    float* ws = (float*)d_ws;
    float* pool_avg = ws;                       // 16384
    float* pool_max = ws + 16384;               // 16384
    float* s        = ws + 32768;               // 16384
    float* cp_max   = ws + 49152;               // 100352
    float* cp_avg   = ws + 149504;              // 100352
    float* g        = ws + 249856;              // 100352  (total 1.37 MB)

    topk_pool_kernel<<<NB * NC / 2, 256, 0, stream>>>(x, pool_avg, pool_max);
    mlp_kernel<<<NB, 256, 0, stream>>>(pool_avg, pool_max, w1, b1, w2, b2, s);
    dim3 grid3((NHW / 4 + 31) / 32, NB);        // (25, 32) = 800 blocks
    spatial_pool_kernel<<<grid3, 256, 0, stream>>>(x, s, cp_max, cp_avg);
    dim3 grid4((NHW + 255) / 256, NB);
    conv_gate_kernel<<<grid4, 256, 0, stream>>>(cp_max, cp_avg, conv_w,
                                                gamma, beta, mean, var, g);
    scale_out_kernel<<<NB * NC, 256, 0, stream>>>(x, s, g, out);
}

// Round 9
// 182.163 us; speedup vs baseline: 1.0213x; 1.0213x over previous
//
#include <hip/hip_runtime.h>
#include <math.h>

// Problem constants (B,C,H,W = 32,512,56,56; top_t = round(3136*0.1) = 314)
#define NB 32
#define NC 512
#define NH 56
#define NW 56
#define NHW 3136
#define TOPT 314
#define NR 32
#define RBUCK 2048
#define SENT 0xFFFFFFFFu

typedef float f32x4 __attribute__((ext_vector_type(4)));

__device__ __forceinline__ unsigned int f2s(float f) {
    unsigned int b = __float_as_uint(f);
    return (b & 0x80000000u) ? ~b : (b | 0x80000000u);
}
__device__ __forceinline__ float s2f(unsigned int u) {
    unsigned int b = (u & 0x80000000u) ? (u ^ 0x80000000u) : ~u;
    return __uint_as_float(b);
}

// ---------------- Kernel 1: exact top-314 sum + max, TWO rows/block ------
// R5/R7 SWAR structure (2 rows/block, packed 16-bit counts; measured best)
// + speculative sign-prune in round 0: only histogram elements >= +0.0
// (sortable u >= 0x80000000). Exact: the p90 threshold bucket is in the
// positive half whenever >=314 positives exist, and then all buckets the
// descending crossing-search inspects hold only histogrammed elements.
// If <314 positives, NO crossing lane fires -> sh_k stays SENT -> retry
// round 0 unpruned (rare path, detected on the existing barrier).
__global__ __launch_bounds__(256) void topk_pool_kernel(
        const float* __restrict__ x,
        float* __restrict__ pool_avg, float* __restrict__ pool_max) {
    __shared__ unsigned int hist[2][RBUCK];      // 16 KB
    __shared__ unsigned int wtot[4];
    __shared__ unsigned int sh_pref[2], sh_k[2];
    __shared__ float redsA[4], redsB[4];
    __shared__ unsigned int redmA[4], redmB[4];

    const int rowA = blockIdx.x * 2;
    const int tid = threadIdx.x;
    const int wid = tid >> 6;
    const int lane = tid & 63;
    const float* xa = x + (size_t)rowA * NHW;
    const float* xb = xa + NHW;
    const float4* xa4 = (const float4*)xa;
    const float4* xb4 = (const float4*)xb;

    // 3136 = 12*256 + 64: three float4 loads + one scalar (tid<64), per row
    float4 a0 = xa4[tid], a1 = xa4[256 + tid], a2 = xa4[512 + tid];
    float4 b0 = xb4[tid], b1 = xb4[256 + tid], b2 = xb4[512 + tid];
    const bool has13 = (tid < 64);
    float exA = has13 ? xa[3072 + tid] : 0.f;
    float exB = has13 ? xb[3072 + tid] : 0.f;

    unsigned int u[13], w[13];
    u[0] = f2s(a0.x); u[1] = f2s(a0.y); u[2]  = f2s(a0.z); u[3]  = f2s(a0.w);
    u[4] = f2s(a1.x); u[5] = f2s(a1.y); u[6]  = f2s(a1.z); u[7]  = f2s(a1.w);
    u[8] = f2s(a2.x); u[9] = f2s(a2.y); u[10] = f2s(a2.z); u[11] = f2s(a2.w);
    u[12] = f2s(exA);
    w[0] = f2s(b0.x); w[1] = f2s(b0.y); w[2]  = f2s(b0.z); w[3]  = f2s(b0.w);
    w[4] = f2s(b1.x); w[5] = f2s(b1.y); w[6]  = f2s(b1.z); w[7]  = f2s(b1.w);
    w[8] = f2s(b2.x); w[9] = f2s(b2.y); w[10] = f2s(b2.z); w[11] = f2s(b2.w);
    w[12] = f2s(exB);

    unsigned int prefA, prefB, kA, kB;

    // ================= round 0 (bits [31:21]) with sign-prune ============
    bool pruned = true;
    for (;;) {
        {   // zero both histogram banks (1024 uint4)
            uint4 z = make_uint4(0u, 0u, 0u, 0u);
            uint4* h0 = (uint4*)hist[0];
            uint4* h1 = (uint4*)hist[1];
            h0[tid] = z; h0[256 + tid] = z;
            h1[tid] = z; h1[256 + tid] = z;
        }
        if (tid == 0) { sh_k[0] = SENT; sh_k[1] = SENT; }
        __syncthreads();
        unsigned int* h = hist[wid >> 1];
        #pragma unroll
        for (int j = 0; j < 13; ++j) {
            const bool live = (j < 12) || has13;
            if (live && (!pruned || (u[j] & 0x80000000u)))
                atomicAdd(&h[u[j] >> 21], 1u);
            if (live && (!pruned || (w[j] & 0x80000000u)))
                atomicAdd(&h[w[j] >> 21], 65536u);
        }
        __syncthreads();
        // fold 8 buckets/thread (both banks) into registers
        unsigned int vv[8];
        unsigned int g = 0u;
        #pragma unroll
        for (int bb = 0; bb < 8; ++bb) {
            vv[bb] = hist[0][8 * tid + bb] + hist[1][8 * tid + bb];
            g += vv[bb];
        }
        // packed suffix-inclusive scan over threads
        unsigned int S = g;
        #pragma unroll
        for (int off = 1; off < 64; off <<= 1) {
            unsigned int t2 = __shfl_down(S, off);
            if (lane + off < 64) S += t2;
        }
        if (lane == 0) wtot[wid] = S;
        __syncthreads();
        unsigned int hi = 0u;
        if (wid < 3) hi += wtot[wid + 1];
        if (wid < 2) hi += wtot[wid + 2];
        if (wid < 1) hi += wtot[wid + 3];
        S += hi;
        const unsigned int SloT = S & 0xFFFFu, ShiT = S >> 16;
        const unsigned int gLo = g & 0xFFFFu,  gHi = g >> 16;
        const unsigned int aboveLo = SloT - gLo, aboveHi = ShiT - gHi;
        if (SloT >= TOPT && aboveLo < TOPT) {
            unsigned int cum = aboveLo;
            #pragma unroll
            for (int bb = 7; bb >= 0; --bb) {
                const unsigned int hh = vv[bb] & 0xFFFFu;
                if (cum + hh >= TOPT) {
                    sh_pref[0] = (unsigned int)(8 * tid + bb) << 21;
                    sh_k[0] = TOPT - cum;
                    break;
                }
                cum += hh;
            }
        }
        if (ShiT >= TOPT && aboveHi < TOPT) {
            unsigned int cum = aboveHi;
            #pragma unroll
            for (int bb = 7; bb >= 0; --bb) {
                const unsigned int hh = vv[bb] >> 16;
                if (cum + hh >= TOPT) {
                    sh_pref[1] = (unsigned int)(8 * tid + bb) << 21;
                    sh_k[1] = TOPT - cum;
                    break;
                }
                cum += hh;
            }
        }
        __syncthreads();
        if (sh_k[0] != SENT && sh_k[1] != SENT) break;
        pruned = false;                      // rare exact fallback, redo both
    }
    prefA = sh_pref[0]; kA = sh_k[0];
    prefB = sh_pref[1]; kB = sh_k[1];

    // ================= rounds 1-2 (bits [20:10], [10:0]) =================
    const int shifts2[2] = {10, 0};
    const unsigned int masks2[2] = {0xFFE00000u, 0xFFFFFC00u};
    #pragma unroll
    for (int r = 0; r < 2; ++r) {
        const int shift = shifts2[r];
        const unsigned int mask = masks2[r];
        {   // zero hist[0] (512 uint4)
            uint4 z = make_uint4(0u, 0u, 0u, 0u);
            uint4* h0 = (uint4*)hist[0];
            h0[tid] = z; h0[256 + tid] = z;
        }
        __syncthreads();
        #pragma unroll
        for (int j = 0; j < 13; ++j) {
            const bool live = (j < 12) || has13;
            if (live && ((u[j] & mask) == prefA))
                atomicAdd(&hist[0][(u[j] >> shift) & (RBUCK - 1u)], 1u);
            if (live && ((w[j] & mask) == prefB))
                atomicAdd(&hist[0][(w[j] >> shift) & (RBUCK - 1u)], 65536u);
        }
        __syncthreads();
        unsigned int vv[8];
        unsigned int g = 0u;
        #pragma unroll
        for (int bb = 0; bb < 8; ++bb) { vv[bb] = hist[0][8 * tid + bb]; g += vv[bb]; }
        unsigned int S = g;
        #pragma unroll
        for (int off = 1; off < 64; off <<= 1) {
            unsigned int t2 = __shfl_down(S, off);
            if (lane + off < 64) S += t2;
        }
        if (lane == 0) wtot[wid] = S;
        __syncthreads();
        unsigned int hi = 0u;
        if (wid < 3) hi += wtot[wid + 1];
        if (wid < 2) hi += wtot[wid + 2];
        if (wid < 1) hi += wtot[wid + 3];
        S += hi;
        const unsigned int SloT = S & 0xFFFFu, ShiT = S >> 16;
        const unsigned int gLo = g & 0xFFFFu,  gHi = g >> 16;
        const unsigned int aboveLo = SloT - gLo, aboveHi = ShiT - gHi;
        if (SloT >= kA && aboveLo < kA) {
            unsigned int cum = aboveLo;
            #pragma unroll
            for (int bb = 7; bb >= 0; --bb) {
                const unsigned int hh = vv[bb] & 0xFFFFu;
                if (cum + hh >= kA) {
                    sh_pref[0] = prefA | ((unsigned int)(8 * tid + bb) << shift);
                    sh_k[0] = kA - cum;
                    break;
                }
                cum += hh;
            }
        }
        if (ShiT >= kB && aboveHi < kB) {
            unsigned int cum = aboveHi;
            #pragma unroll
            for (int bb = 7; bb >= 0; --bb) {
                const unsigned int hh = vv[bb] >> 16;
                if (cum + hh >= kB) {
                    sh_pref[1] = prefB | ((unsigned int)(8 * tid + bb) << shift);
                    sh_k[1] = kB - cum;
                    break;
                }
                cum += hh;
            }
        }
        __syncthreads();
        prefA = sh_pref[0]; kA = sh_k[0];
        prefB = sh_pref[1]; kB = sh_k[1];
    }

    // ---- final: per-row sum of elements > t (+ k ties), and row max ----
    const unsigned int tA = prefA, tB = prefB;
    float sumA = 0.f, sumB = 0.f;
    unsigned int mA = 0u, mB = 0u;
    #pragma unroll
    for (int j = 0; j < 13; ++j) {
        const bool live = (j < 12) || has13;
        if (live) {
            mA = max(mA, u[j]);
            if (u[j] > tA) sumA += s2f(u[j]);
            mB = max(mB, w[j]);
            if (w[j] > tB) sumB += s2f(w[j]);
        }
    }
    #pragma unroll
    for (int off = 32; off > 0; off >>= 1) {
        sumA += __shfl_down(sumA, off);
        sumB += __shfl_down(sumB, off);
        mA = max(mA, __shfl_down(mA, off));
        mB = max(mB, __shfl_down(mB, off));
    }
    if (lane == 0) { redsA[wid] = sumA; redsB[wid] = sumB;
                     redmA[wid] = mA;   redmB[wid] = mB; }
    __syncthreads();
    if (tid == 0) {
        float totA = redsA[0] + redsA[1] + redsA[2] + redsA[3] + (float)kA * s2f(tA);
        float totB = redsB[0] + redsB[1] + redsB[2] + redsB[3] + (float)kB * s2f(tB);
        pool_avg[rowA]     = totA * (1.0f / (float)TOPT);
        pool_avg[rowA + 1] = totB * (1.0f / (float)TOPT);
        pool_max[rowA]     = s2f(max(max(redmA[0], redmA[1]), max(redmA[2], redmA[3])));
        pool_max[rowA + 1] = s2f(max(max(redmB[0], redmB[1]), max(redmB[2], redmB[3])));
    }
}

// ---------------- Kernel 2: channel-MLP + sigmoid -> s[b,c] --------------
// Layer 1 uses all 256 threads: 32 units x 2 pools x 4 K-segments of 128,
// partials combined via LDS (was 64 threads x 512 serial MACs).
__global__ __launch_bounds__(256) void mlp_kernel(
        const float* __restrict__ pool_avg, const float* __restrict__ pool_max,
        const float* __restrict__ w1, const float* __restrict__ b1,
        const float* __restrict__ w2, const float* __restrict__ b2,
        float* __restrict__ s_out) {
    __shared__ float pa[NC], pm[NC], part[64][4], h1a[NR], h1m[NR];
    const int b = blockIdx.x, tid = threadIdx.x;
    for (int c = tid; c < NC; c += 256) {
        pa[c] = pool_avg[b * NC + c];
        pm[c] = pool_max[b * NC + c];
    }
    __syncthreads();
    {
        const int r = tid & 31;              // hidden unit
        const int half = (tid >> 5) & 1;     // 0=avg, 1=max
        const int seg = tid >> 6;            // K-segment 0..3
        const float* p = (half ? pm : pa) + seg * 128;
        const float* wrow = w1 + r * NC + seg * 128;
        float acc = 0.f;
        #pragma unroll 4
        for (int c = 0; c < 128; ++c) acc = fmaf(p[c], wrow[c], acc);
        part[tid & 63][seg] = acc;
    }
    __syncthreads();
    if (tid < 64) {
        const int r = tid & 31;
        float acc = b1[r] + part[tid][0] + part[tid][1]
                  + part[tid][2] + part[tid][3];
        float h = fmaxf(acc, 0.f);
        if (tid < 32) h1a[r] = h; else h1m[r] = h;
    }
    __syncthreads();
    for (int c = tid; c < NC; c += 256) {
        float acc = 2.f * b2[c];
        const float* wrow = w2 + c * NR;
        for (int r = 0; r < NR; ++r) acc += (h1a[r] + h1m[r]) * wrow[r];
        s_out[b * NC + c] = 1.f / (1.f + expf(-acc));
    }
}

// ---------------- Kernel 3: channel max/mean of x*s -> cp ----------------
__global__ __launch_bounds__(256) void spatial_pool_kernel(
        const float* __restrict__ x, const float* __restrict__ s,
        float* __restrict__ cp_max, float* __restrict__ cp_avg) {
    __shared__ float sc[NC];
    __shared__ float4 pmx[7][32];
    __shared__ float4 psm[7][32];
    const int b = blockIdx.y, tid = threadIdx.x;
    const int qo = tid & 31;                 // float4-pixel within tile
    const int cg = tid >> 5;                 // channel group 0..7
    const int q = blockIdx.x * 32 + qo;      // float4 index, 0..783 valid
    for (int c = tid; c < NC; c += 256) sc[c] = s[b * NC + c];
    __syncthreads();
    const float4* xb4 = (const float4*)(x + (size_t)b * NC * NHW);
    float4 mx = make_float4(-INFINITY, -INFINITY, -INFINITY, -INFINITY);
    float4 sm = make_float4(0.f, 0.f, 0.f, 0.f);
    const bool valid = (q < NHW / 4);
    if (valid) {
        #pragma unroll 2
        for (int c = cg * 64; c < cg * 64 + 64; ++c) {
            float4 v = xb4[(size_t)c * (NHW / 4) + q];
            const float scv = sc[c];
            v.x *= scv; v.y *= scv; v.z *= scv; v.w *= scv;
            mx.x = fmaxf(mx.x, v.x); mx.y = fmaxf(mx.y, v.y);
            mx.z = fmaxf(mx.z, v.z); mx.w = fmaxf(mx.w, v.w);
            sm.x += v.x; sm.y += v.y; sm.z += v.z; sm.w += v.w;
        }
    }
    if (cg > 0 && valid) { pmx[cg - 1][qo] = mx; psm[cg - 1][qo] = sm; }
    __syncthreads();
    if (cg == 0 && valid) {
        #pragma unroll
        for (int i = 0; i < 7; ++i) {
            const float4 m2 = pmx[i][qo];
            const float4 s2 = psm[i][qo];
            mx.x = fmaxf(mx.x, m2.x); mx.y = fmaxf(mx.y, m2.y);
            mx.z = fmaxf(mx.z, m2.z); mx.w = fmaxf(mx.w, m2.w);
            sm.x += s2.x; sm.y += s2.y; sm.z += s2.z; sm.w += s2.w;
        }
        const float inv = 1.0f / (float)NC;
        sm.x *= inv; sm.y *= inv; sm.z *= inv; sm.w *= inv;
        ((float4*)(cp_max + b * NHW))[q] = mx;
        ((float4*)(cp_avg + b * NHW))[q] = sm;
    }
}

// ---------------- Kernel 4: 7x7 conv + BN + sigmoid -> g[b,hw] -----------
__global__ __launch_bounds__(256) void conv_gate_kernel(
        const float* __restrict__ cp_max, const float* __restrict__ cp_avg,
        const float* __restrict__ conv_w,
        const float* __restrict__ gamma, const float* __restrict__ beta,
        const float* __restrict__ mean, const float* __restrict__ var,
        float* __restrict__ g) {
    __shared__ float wgt[98];
    const int b = blockIdx.y, tid = threadIdx.x;
    const int p = blockIdx.x * 256 + tid;
    if (tid < 98) wgt[tid] = conv_w[tid];
    __syncthreads();
    if (p >= NHW) return;
    const int h = p / NW, w = p - h * NW;
    const float* cm = cp_max + b * NHW;
    const float* ca = cp_avg + b * NHW;
    float acc = 0.f;
    for (int i = 0; i < 7; ++i) {
        const int hh = h - 3 + i;
        if (hh < 0 || hh >= NH) continue;
        for (int j = 0; j < 7; ++j) {
            const int ww = w - 3 + j;
            if (ww < 0 || ww >= NW) continue;
            const int q = hh * NW + ww;
            acc += cm[q] * wgt[i * 7 + j] + ca[q] * wgt[49 + i * 7 + j];
        }
    }
    const float bnv = (acc - mean[0]) * rsqrtf(var[0] + 1e-5f) * gamma[0] + beta[0];
    g[b * NHW + p] = 1.f / (1.f + expf(-bnv));
}

// ---------------- Kernel 5: out = x * s[b,c] * g[b,hw] -------------------
__global__ __launch_bounds__(256) void scale_out_kernel(
        const float* __restrict__ x, const float* __restrict__ s,
        const float* __restrict__ g, float* __restrict__ out) {
    const int bc = blockIdx.x;               // 0..16383
    const int b = bc >> 9;
    const int tid = threadIdx.x;
    const float sv = s[bc];
    const f32x4* xr = (const f32x4*)(x + (size_t)bc * NHW);
    const f32x4* gr = (const f32x4*)(g + (size_t)b * NHW);
    f32x4* orow = (f32x4*)(out + (size_t)bc * NHW);
    #pragma unroll
    for (int i = 0; i < 3; ++i) {            // 3*256 = 768 of 784 float4s
        const int q = tid + 256 * i;
        f32x4 xv = xr[q];
        f32x4 gv = gr[q];
        f32x4 ov = xv * sv * gv;
        __builtin_nontemporal_store(ov, &orow[q]);
    }
    if (tid < 16) {                          // tail: 768..783
        const int q = 768 + tid;
        f32x4 xv = xr[q];
        f32x4 gv = gr[q];
        f32x4 ov = xv * sv * gv;
        __builtin_nontemporal_store(ov, &orow[q]);
    }
}

extern "C" void kernel_launch(void* const* d_in, const int* in_sizes, int n_in,
                              void* d_out, int out_size, void* d_ws, size_t ws_size,
                              hipStream_t stream) {
    const float* x      = (const float*)d_in[0];
    const float* w1     = (const float*)d_in[1];
    const float* b1     = (const float*)d_in[2];
    const float* w2     = (const float*)d_in[3];
    const float* b2     = (const float*)d_in[4];
    const float* conv_w = (const float*)d_in[5];
    const float* gamma  = (const float*)d_in[6];
    const float* beta   = (const float*)d_in[7];
    const float* mean   = (const float*)d_in[8];
    const float* var    = (const float*)d_in[9];
    float* out = (float*)d_out;

    float* ws = (float*)d_ws;
    float* pool_avg = ws;                       // 16384
    float* pool_max = ws + 16384;               // 16384
    float* s        = ws + 32768;               // 16384
    float* cp_max   = ws + 49152;               // 100352
    float* cp_avg   = ws + 149504;              // 100352
    float* g        = ws + 249856;              // 100352  (total 1.37 MB)

    topk_pool_kernel<<<NB * NC / 2, 256, 0, stream>>>(x, pool_avg, pool_max);
    mlp_kernel<<<NB, 256, 0, stream>>>(pool_avg, pool_max, w1, b1, w2, b2, s);
    dim3 grid3((NHW / 4 + 31) / 32, NB);        // (25, 32) = 800 blocks
    spatial_pool_kernel<<<grid3, 256, 0, stream>>>(x, s, cp_max, cp_avg);
    dim3 grid4((NHW + 255) / 256, NB);
    conv_gate_kernel<<<grid4, 256, 0, stream>>>(cp_max, cp_avg, conv_w,
                                                gamma, beta, mean, var, g);
    scale_out_kernel<<<NB * NC, 256, 0, stream>>>(x, s, g, out);
}

// Round 10
// 172.426 us; speedup vs baseline: 1.0790x; 1.0565x over previous
//
#include <hip/hip_runtime.h>
#include <math.h>

// Problem constants (B,C,H,W = 32,512,56,56; top_t = round(3136*0.1) = 314)
#define NB 32
#define NC 512
#define NH 56
#define NW 56
#define NHW 3136
#define TOPT 314
#define NR 32
#define RBUCK 2048

typedef float f32x4 __attribute__((ext_vector_type(4)));

__device__ __forceinline__ unsigned int f2s(float f) {
    unsigned int b = __float_as_uint(f);
    return (b & 0x80000000u) ? ~b : (b | 0x80000000u);
}
__device__ __forceinline__ float s2f(unsigned int u) {
    unsigned int b = (u & 0x80000000u) ? (u ^ 0x80000000u) : ~u;
    return __uint_as_float(b);
}

// ---------------- Kernel 1: exact top-314 sum + max, TWO rows/block ------
// R5/R7 config — measured best (176.8 us total). 26 data regs/thread keeps
// VGPR < 64 -> 8 waves/SIMD; SWAR-packed shared histograms amortize
// zero/fold/scan/barrier over 2 rows. Variants that regressed: wave-private
// histograms (R6 +10us), stats-based quantile prune + bank permute (R8
// +9us), sign-pruned round 0 with retry loop (R9 +5us). The barrier-phase
// skeleton, not LDS atomic traffic, is the floor here — leave it alone.
// Rows 2*blk and 2*blk+1 share one SWAR-packed histogram: row A counts in
// bits[15:0], row B in bits[31:16] (3136 < 65536 so halves never carry).
// 3-round 11-bit radix select; packed suffix scan finds each row's
// threshold bucket; exact tie handling via k*val(t).
__global__ __launch_bounds__(256) void topk_pool_kernel(
        const float* __restrict__ x,
        float* __restrict__ pool_avg, float* __restrict__ pool_max) {
    __shared__ unsigned int hist[2][RBUCK];      // 16 KB
    __shared__ unsigned int wtot[4];
    __shared__ unsigned int sh_pref[2], sh_k[2];
    __shared__ float redsA[4], redsB[4];
    __shared__ unsigned int redmA[4], redmB[4];

    const int rowA = blockIdx.x * 2;
    const int tid = threadIdx.x;
    const int wid = tid >> 6;
    const int lane = tid & 63;
    const float* xa = x + (size_t)rowA * NHW;
    const float* xb = xa + NHW;
    const float4* xa4 = (const float4*)xa;
    const float4* xb4 = (const float4*)xb;

    // 3136 = 12*256 + 64: three float4 loads + one scalar (tid<64), per row
    float4 a0 = xa4[tid], a1 = xa4[256 + tid], a2 = xa4[512 + tid];
    float4 b0 = xb4[tid], b1 = xb4[256 + tid], b2 = xb4[512 + tid];
    const bool has13 = (tid < 64);
    float exA = has13 ? xa[3072 + tid] : 0.f;
    float exB = has13 ? xb[3072 + tid] : 0.f;

    unsigned int u[13], w[13];
    u[0] = f2s(a0.x); u[1] = f2s(a0.y); u[2]  = f2s(a0.z); u[3]  = f2s(a0.w);
    u[4] = f2s(a1.x); u[5] = f2s(a1.y); u[6]  = f2s(a1.z); u[7]  = f2s(a1.w);
    u[8] = f2s(a2.x); u[9] = f2s(a2.y); u[10] = f2s(a2.z); u[11] = f2s(a2.w);
    u[12] = f2s(exA);
    w[0] = f2s(b0.x); w[1] = f2s(b0.y); w[2]  = f2s(b0.z); w[3]  = f2s(b0.w);
    w[4] = f2s(b1.x); w[5] = f2s(b1.y); w[6]  = f2s(b1.z); w[7]  = f2s(b1.w);
    w[8] = f2s(b2.x); w[9] = f2s(b2.y); w[10] = f2s(b2.z); w[11] = f2s(b2.w);
    w[12] = f2s(exB);

    unsigned int prefA = 0u, prefB = 0u, mask = 0u;
    unsigned int kA = TOPT, kB = TOPT;
    const int shifts[3] = {21, 10, 0};
    #pragma unroll
    for (int r = 0; r < 3; ++r) {
        const int shift = shifts[r];
        {   // zero histogram(s)
            uint4 z = make_uint4(0u, 0u, 0u, 0u);
            uint4* h0 = (uint4*)hist[0];
            h0[tid] = z; h0[256 + tid] = z;
            if (r == 0) {
                uint4* h1 = (uint4*)hist[1];
                h1[tid] = z; h1[256 + tid] = z;
            }
        }
        __syncthreads();
        unsigned int* h = (r == 0) ? hist[wid >> 1] : hist[0];
        #pragma unroll
        for (int j = 0; j < 13; ++j) {
            const bool live = (j < 12) || has13;
            if (live && ((u[j] & mask) == prefA))
                atomicAdd(&h[(u[j] >> shift) & (RBUCK - 1u)], 1u);
            if (live && ((w[j] & mask) == prefB))
                atomicAdd(&h[(w[j] >> shift) & (RBUCK - 1u)], 65536u);
        }
        __syncthreads();

        // fold 8 buckets/thread into registers (packed counts)
        unsigned int vv[8];
        unsigned int g = 0u;
        if (r == 0) {
            #pragma unroll
            for (int bb = 0; bb < 8; ++bb) {
                vv[bb] = hist[0][8 * tid + bb] + hist[1][8 * tid + bb];
                g += vv[bb];
            }
        } else {
            #pragma unroll
            for (int bb = 0; bb < 8; ++bb) { vv[bb] = hist[0][8 * tid + bb]; g += vv[bb]; }
        }
        // packed suffix-inclusive scan over threads
        unsigned int S = g;
        #pragma unroll
        for (int off = 1; off < 64; off <<= 1) {
            unsigned int t2 = __shfl_down(S, off);
            if (lane + off < 64) S += t2;
        }
        if (lane == 0) wtot[wid] = S;
        __syncthreads();
        unsigned int hi = 0u;
        if (wid < 3) hi += wtot[wid + 1];
        if (wid < 2) hi += wtot[wid + 2];
        if (wid < 1) hi += wtot[wid + 3];
        S += hi;                               // packed: count in buckets >= mine
        const unsigned int SloT = S & 0xFFFFu, ShiT = S >> 16;
        const unsigned int gLo = g & 0xFFFFu,  gHi = g >> 16;
        const unsigned int aboveLo = SloT - gLo, aboveHi = ShiT - gHi;
        if (SloT >= kA && aboveLo < kA) {      // unique crossing thread, row A
            unsigned int cum = aboveLo;
            #pragma unroll
            for (int bb = 7; bb >= 0; --bb) {
                const unsigned int hh = vv[bb] & 0xFFFFu;
                if (cum + hh >= kA) {
                    sh_pref[0] = prefA | ((unsigned int)(8 * tid + bb) << shift);
                    sh_k[0] = kA - cum;
                    break;
                }
                cum += hh;
            }
        }
        if (ShiT >= kB && aboveHi < kB) {      // row B
            unsigned int cum = aboveHi;
            #pragma unroll
            for (int bb = 7; bb >= 0; --bb) {
                const unsigned int hh = vv[bb] >> 16;
                if (cum + hh >= kB) {
                    sh_pref[1] = prefB | ((unsigned int)(8 * tid + bb) << shift);
                    sh_k[1] = kB - cum;
                    break;
                }
                cum += hh;
            }
        }
        __syncthreads();
        prefA = sh_pref[0]; kA = sh_k[0];
        prefB = sh_pref[1]; kB = sh_k[1];
        mask = 0xFFFFFFFFu << shift;
    }

    // ---- final: per-row sum of elements > t (+ k ties), and row max ----
    const unsigned int tA = prefA, tB = prefB;
    float sumA = 0.f, sumB = 0.f;
    unsigned int mA = 0u, mB = 0u;
    #pragma unroll
    for (int j = 0; j < 13; ++j) {
        const bool live = (j < 12) || has13;
        if (live) {
            mA = max(mA, u[j]);
            if (u[j] > tA) sumA += s2f(u[j]);
            mB = max(mB, w[j]);
            if (w[j] > tB) sumB += s2f(w[j]);
        }
    }
    #pragma unroll
    for (int off = 32; off > 0; off >>= 1) {
        sumA += __shfl_down(sumA, off);
        sumB += __shfl_down(sumB, off);
        mA = max(mA, __shfl_down(mA, off));
        mB = max(mB, __shfl_down(mB, off));
    }
    if (lane == 0) { redsA[wid] = sumA; redsB[wid] = sumB;
                     redmA[wid] = mA;   redmB[wid] = mB; }
    __syncthreads();
    if (tid == 0) {
        float totA = redsA[0] + redsA[1] + redsA[2] + redsA[3] + (float)kA * s2f(tA);
        float totB = redsB[0] + redsB[1] + redsB[2] + redsB[3] + (float)kB * s2f(tB);
        pool_avg[rowA]     = totA * (1.0f / (float)TOPT);
        pool_avg[rowA + 1] = totB * (1.0f / (float)TOPT);
        pool_max[rowA]     = s2f(max(max(redmA[0], redmA[1]), max(redmA[2], redmA[3])));
        pool_max[rowA + 1] = s2f(max(max(redmB[0], redmB[1]), max(redmB[2], redmB[3])));
    }
}

// ---------------- Kernel 2: channel-MLP + sigmoid -> s[b,c] --------------
// Layer 1 uses all 256 threads: 32 units x 2 pools x 4 K-segments of 128,
// partials combined via LDS (isolated change vs R7's 64-thread version).
__global__ __launch_bounds__(256) void mlp_kernel(
        const float* __restrict__ pool_avg, const float* __restrict__ pool_max,
        const float* __restrict__ w1, const float* __restrict__ b1,
        const float* __restrict__ w2, const float* __restrict__ b2,
        float* __restrict__ s_out) {
    __shared__ float pa[NC], pm[NC], part[64][4], h1a[NR], h1m[NR];
    const int b = blockIdx.x, tid = threadIdx.x;
    for (int c = tid; c < NC; c += 256) {
        pa[c] = pool_avg[b * NC + c];
        pm[c] = pool_max[b * NC + c];
    }
    __syncthreads();
    {
        const int r = tid & 31;              // hidden unit
        const int half = (tid >> 5) & 1;     // 0=avg, 1=max
        const int seg = tid >> 6;            // K-segment 0..3
        const float* p = (half ? pm : pa) + seg * 128;
        const float* wrow = w1 + r * NC + seg * 128;
        float acc = 0.f;
        #pragma unroll 4
        for (int c = 0; c < 128; ++c) acc = fmaf(p[c], wrow[c], acc);
        part[tid & 63][seg] = acc;
    }
    __syncthreads();
    if (tid < 64) {
        const int r = tid & 31;
        float acc = b1[r] + part[tid][0] + part[tid][1]
                  + part[tid][2] + part[tid][3];
        float h = fmaxf(acc, 0.f);
        if (tid < 32) h1a[r] = h; else h1m[r] = h;
    }
    __syncthreads();
    for (int c = tid; c < NC; c += 256) {
        float acc = 2.f * b2[c];
        const float* wrow = w2 + c * NR;
        for (int r = 0; r < NR; ++r) acc += (h1a[r] + h1m[r]) * wrow[r];
        s_out[b * NC + c] = 1.f / (1.f + expf(-acc));
    }
}

// ---------------- Kernel 3: channel max/mean of x*s -> cp ----------------
__global__ __launch_bounds__(256) void spatial_pool_kernel(
        const float* __restrict__ x, const float* __restrict__ s,
        float* __restrict__ cp_max, float* __restrict__ cp_avg) {
    __shared__ float sc[NC];
    __shared__ float4 pmx[7][32];
    __shared__ float4 psm[7][32];
    const int b = blockIdx.y, tid = threadIdx.x;
    const int qo = tid & 31;                 // float4-pixel within tile
    const int cg = tid >> 5;                 // channel group 0..7
    const int q = blockIdx.x * 32 + qo;      // float4 index, 0..783 valid
    for (int c = tid; c < NC; c += 256) sc[c] = s[b * NC + c];
    __syncthreads();
    const float4* xb4 = (const float4*)(x + (size_t)b * NC * NHW);
    float4 mx = make_float4(-INFINITY, -INFINITY, -INFINITY, -INFINITY);
    float4 sm = make_float4(0.f, 0.f, 0.f, 0.f);
    const bool valid = (q < NHW / 4);
    if (valid) {
        #pragma unroll 2
        for (int c = cg * 64; c < cg * 64 + 64; ++c) {
            float4 v = xb4[(size_t)c * (NHW / 4) + q];
            const float scv = sc[c];
            v.x *= scv; v.y *= scv; v.z *= scv; v.w *= scv;
            mx.x = fmaxf(mx.x, v.x); mx.y = fmaxf(mx.y, v.y);
            mx.z = fmaxf(mx.z, v.z); mx.w = fmaxf(mx.w, v.w);
            sm.x += v.x; sm.y += v.y; sm.z += v.z; sm.w += v.w;
        }
    }
    if (cg > 0 && valid) { pmx[cg - 1][qo] = mx; psm[cg - 1][qo] = sm; }
    __syncthreads();
    if (cg == 0 && valid) {
        #pragma unroll
        for (int i = 0; i < 7; ++i) {
            const float4 m2 = pmx[i][qo];
            const float4 s2 = psm[i][qo];
            mx.x = fmaxf(mx.x, m2.x); mx.y = fmaxf(mx.y, m2.y);
            mx.z = fmaxf(mx.z, m2.z); mx.w = fmaxf(mx.w, m2.w);
            sm.x += s2.x; sm.y += s2.y; sm.z += s2.z; sm.w += s2.w;
        }
        const float inv = 1.0f / (float)NC;
        sm.x *= inv; sm.y *= inv; sm.z *= inv; sm.w *= inv;
        ((float4*)(cp_max + b * NHW))[q] = mx;
        ((float4*)(cp_avg + b * NHW))[q] = sm;
    }
}

// ---------------- Kernel 4: 7x7 conv + BN + sigmoid -> g[b,hw] -----------
__global__ __launch_bounds__(256) void conv_gate_kernel(
        const float* __restrict__ cp_max, const float* __restrict__ cp_avg,
        const float* __restrict__ conv_w,
        const float* __restrict__ gamma, const float* __restrict__ beta,
        const float* __restrict__ mean, const float* __restrict__ var,
        float* __restrict__ g) {
    __shared__ float wgt[98];
    const int b = blockIdx.y, tid = threadIdx.x;
    const int p = blockIdx.x * 256 + tid;
    if (tid < 98) wgt[tid] = conv_w[tid];
    __syncthreads();
    if (p >= NHW) return;
    const int h = p / NW, w = p - h * NW;
    const float* cm = cp_max + b * NHW;
    const float* ca = cp_avg + b * NHW;
    float acc = 0.f;
    for (int i = 0; i < 7; ++i) {
        const int hh = h - 3 + i;
        if (hh < 0 || hh >= NH) continue;
        for (int j = 0; j < 7; ++j) {
            const int ww = w - 3 + j;
            if (ww < 0 || ww >= NW) continue;
            const int q = hh * NW + ww;
            acc += cm[q] * wgt[i * 7 + j] + ca[q] * wgt[49 + i * 7 + j];
        }
    }
    const float bnv = (acc - mean[0]) * rsqrtf(var[0] + 1e-5f) * gamma[0] + beta[0];
    g[b * NHW + p] = 1.f / (1.f + expf(-bnv));
}

// ---------------- Kernel 5: out = x * s[b,c] * g[b,hw] -------------------
// One block per (b,c) row: scalar s broadcast, nontemporal stores so the
// 205 MB output stream doesn't evict x from L3.
__global__ __launch_bounds__(256) void scale_out_kernel(
        const float* __restrict__ x, const float* __restrict__ s,
        const float* __restrict__ g, float* __restrict__ out) {
    const int bc = blockIdx.x;               // 0..16383
    const int b = bc >> 9;
    const int tid = threadIdx.x;
    const float sv = s[bc];
    const f32x4* xr = (const f32x4*)(x + (size_t)bc * NHW);
    const f32x4* gr = (const f32x4*)(g + (size_t)b * NHW);
    f32x4* orow = (f32x4*)(out + (size_t)bc * NHW);
    #pragma unroll
    for (int i = 0; i < 3; ++i) {            // 3*256 = 768 of 784 float4s
        const int q = tid + 256 * i;
        f32x4 xv = xr[q];
        f32x4 gv = gr[q];
        f32x4 ov = xv * sv * gv;
        __builtin_nontemporal_store(ov, &orow[q]);
    }
    if (tid < 16) {                          // tail: 768..783
        const int q = 768 + tid;
        f32x4 xv = xr[q];
        f32x4 gv = gr[q];
        f32x4 ov = xv * sv * gv;
        __builtin_nontemporal_store(ov, &orow[q]);
    }
}

extern "C" void kernel_launch(void* const* d_in, const int* in_sizes, int n_in,
                              void* d_out, int out_size, void* d_ws, size_t ws_size,
                              hipStream_t stream) {
    const float* x      = (const float*)d_in[0];
    const float* w1     = (const float*)d_in[1];
    const float* b1     = (const float*)d_in[2];
    const float* w2     = (const float*)d_in[3];
    const float* b2     = (const float*)d_in[4];
    const float* conv_w = (const float*)d_in[5];
    const float* gamma  = (const float*)d_in[6];
    const float* beta   = (const float*)d_in[7];
    const float* mean   = (const float*)d_in[8];
    const float* var    = (const float*)d_in[9];
    float* out = (float*)d_out;

    float* ws = (float*)d_ws;
    float* pool_avg = ws;                       // 16384
    float* pool_max = ws + 16384;               // 16384
    float* s        = ws + 32768;               // 16384
    float* cp_max   = ws + 49152;               // 100352
    float* cp_avg   = ws + 149504;              // 100352
    float* g        = ws + 249856;              // 100352  (total 1.37 MB)

    topk_pool_kernel<<<NB * NC / 2, 256, 0, stream>>>(x, pool_avg, pool_max);
    mlp_kernel<<<NB, 256, 0, stream>>>(pool_avg, pool_max, w1, b1, w2, b2, s);
    dim3 grid3((NHW / 4 + 31) / 32, NB);        // (25, 32) = 800 blocks
    spatial_pool_kernel<<<grid3, 256, 0, stream>>>(x, s, cp_max, cp_avg);
    dim3 grid4((NHW + 255) / 256, NB);
    conv_gate_kernel<<<grid4, 256, 0, stream>>>(cp_max, cp_avg, conv_w,
                                                gamma, beta, mean, var, g);
    scale_out_kernel<<<NB * NC, 256, 0, stream>>>(x, s, g, out);
}

// Round 11
// 170.657 us; speedup vs baseline: 1.0902x; 1.0104x over previous
//
#include <hip/hip_runtime.h>
#include <math.h>

// Problem constants (B,C,H,W = 32,512,56,56; top_t = round(3136*0.1) = 314)
#define NB 32
#define NC 512
#define NH 56
#define NW 56
#define NHW 3136
#define TOPT 314
#define NR 32
#define RBUCK 2048

typedef float f32x4 __attribute__((ext_vector_type(4)));

__device__ __forceinline__ unsigned int f2s(float f) {
    unsigned int b = __float_as_uint(f);
    return (b & 0x80000000u) ? ~b : (b | 0x80000000u);
}
__device__ __forceinline__ float s2f(unsigned int u) {
    unsigned int b = (u & 0x80000000u) ? (u ^ 0x80000000u) : ~u;
    return __uint_as_float(b);
}

// ---------------- Kernel 1: exact top-314 sum + max, TWO rows/block ------
// R5/R7/R10 skeleton (measured best; wave-private hist, quantile prune,
// sign-prune retry all regressed). ONE change vs R10: round-0 histogram
// bank selected by LANE PARITY (hist[lane&1]) instead of wave-pair
// (hist[wid>>1]). SQ_LDS_BANK_CONFLICT is data-invariant at 1.84e7 across
// all layouts -> dominated by same-address atomic RMW serialization on hot
// buckets; splitting each atomic instruction's 64 lanes across two bucket
// copies halves the per-address collision degree. (The resulting 2-way
// LDS bank alias between copies is free.) Fold already sums both banks.
// Rows 2*blk and 2*blk+1 share one SWAR-packed histogram: row A counts in
// bits[15:0], row B in bits[31:16] (3136 < 65536 so halves never carry).
// 3-round 11-bit radix select; packed suffix scan finds each row's
// threshold bucket; exact tie handling via k*val(t).
__global__ __launch_bounds__(256) void topk_pool_kernel(
        const float* __restrict__ x,
        float* __restrict__ pool_avg, float* __restrict__ pool_max) {
    __shared__ unsigned int hist[2][RBUCK];      // 16 KB
    __shared__ unsigned int wtot[4];
    __shared__ unsigned int sh_pref[2], sh_k[2];
    __shared__ float redsA[4], redsB[4];
    __shared__ unsigned int redmA[4], redmB[4];

    const int rowA = blockIdx.x * 2;
    const int tid = threadIdx.x;
    const int wid = tid >> 6;
    const int lane = tid & 63;
    const float* xa = x + (size_t)rowA * NHW;
    const float* xb = xa + NHW;
    const float4* xa4 = (const float4*)xa;
    const float4* xb4 = (const float4*)xb;

    // 3136 = 12*256 + 64: three float4 loads + one scalar (tid<64), per row
    float4 a0 = xa4[tid], a1 = xa4[256 + tid], a2 = xa4[512 + tid];
    float4 b0 = xb4[tid], b1 = xb4[256 + tid], b2 = xb4[512 + tid];
    const bool has13 = (tid < 64);
    float exA = has13 ? xa[3072 + tid] : 0.f;
    float exB = has13 ? xb[3072 + tid] : 0.f;

    unsigned int u[13], w[13];
    u[0] = f2s(a0.x); u[1] = f2s(a0.y); u[2]  = f2s(a0.z); u[3]  = f2s(a0.w);
    u[4] = f2s(a1.x); u[5] = f2s(a1.y); u[6]  = f2s(a1.z); u[7]  = f2s(a1.w);
    u[8] = f2s(a2.x); u[9] = f2s(a2.y); u[10] = f2s(a2.z); u[11] = f2s(a2.w);
    u[12] = f2s(exA);
    w[0] = f2s(b0.x); w[1] = f2s(b0.y); w[2]  = f2s(b0.z); w[3]  = f2s(b0.w);
    w[4] = f2s(b1.x); w[5] = f2s(b1.y); w[6]  = f2s(b1.z); w[7]  = f2s(b1.w);
    w[8] = f2s(b2.x); w[9] = f2s(b2.y); w[10] = f2s(b2.z); w[11] = f2s(b2.w);
    w[12] = f2s(exB);

    unsigned int prefA = 0u, prefB = 0u, mask = 0u;
    unsigned int kA = TOPT, kB = TOPT;
    const int shifts[3] = {21, 10, 0};
    #pragma unroll
    for (int r = 0; r < 3; ++r) {
        const int shift = shifts[r];
        {   // zero histogram(s)
            uint4 z = make_uint4(0u, 0u, 0u, 0u);
            uint4* h0 = (uint4*)hist[0];
            h0[tid] = z; h0[256 + tid] = z;
            if (r == 0) {
                uint4* h1 = (uint4*)hist[1];
                h1[tid] = z; h1[256 + tid] = z;
            }
        }
        __syncthreads();
        // round 0: split same-bucket atomics across two copies by lane
        // parity (halves same-address RMW serialization); rounds 1-2:
        // single bank (few survivors -> negligible collisions)
        unsigned int* h = (r == 0) ? hist[lane & 1] : hist[0];
        #pragma unroll
        for (int j = 0; j < 13; ++j) {
            const bool live = (j < 12) || has13;
            if (live && ((u[j] & mask) == prefA))
                atomicAdd(&h[(u[j] >> shift) & (RBUCK - 1u)], 1u);
            if (live && ((w[j] & mask) == prefB))
                atomicAdd(&h[(w[j] >> shift) & (RBUCK - 1u)], 65536u);
        }
        __syncthreads();

        // fold 8 buckets/thread into registers (packed counts)
        unsigned int vv[8];
        unsigned int g = 0u;
        if (r == 0) {
            #pragma unroll
            for (int bb = 0; bb < 8; ++bb) {
                vv[bb] = hist[0][8 * tid + bb] + hist[1][8 * tid + bb];
                g += vv[bb];
            }
        } else {
            #pragma unroll
            for (int bb = 0; bb < 8; ++bb) { vv[bb] = hist[0][8 * tid + bb]; g += vv[bb]; }
        }
        // packed suffix-inclusive scan over threads
        unsigned int S = g;
        #pragma unroll
        for (int off = 1; off < 64; off <<= 1) {
            unsigned int t2 = __shfl_down(S, off);
            if (lane + off < 64) S += t2;
        }
        if (lane == 0) wtot[wid] = S;
        __syncthreads();
        unsigned int hi = 0u;
        if (wid < 3) hi += wtot[wid + 1];
        if (wid < 2) hi += wtot[wid + 2];
        if (wid < 1) hi += wtot[wid + 3];
        S += hi;                               // packed: count in buckets >= mine
        const unsigned int SloT = S & 0xFFFFu, ShiT = S >> 16;
        const unsigned int gLo = g & 0xFFFFu,  gHi = g >> 16;
        const unsigned int aboveLo = SloT - gLo, aboveHi = ShiT - gHi;
        if (SloT >= kA && aboveLo < kA) {      // unique crossing thread, row A
            unsigned int cum = aboveLo;
            #pragma unroll
            for (int bb = 7; bb >= 0; --bb) {
                const unsigned int hh = vv[bb] & 0xFFFFu;
                if (cum + hh >= kA) {
                    sh_pref[0] = prefA | ((unsigned int)(8 * tid + bb) << shift);
                    sh_k[0] = kA - cum;
                    break;
                }
                cum += hh;
            }
        }
        if (ShiT >= kB && aboveHi < kB) {      // row B
            unsigned int cum = aboveHi;
            #pragma unroll
            for (int bb = 7; bb >= 0; --bb) {
                const unsigned int hh = vv[bb] >> 16;
                if (cum + hh >= kB) {
                    sh_pref[1] = prefB | ((unsigned int)(8 * tid + bb) << shift);
                    sh_k[1] = kB - cum;
                    break;
                }
                cum += hh;
            }
        }
        __syncthreads();
        prefA = sh_pref[0]; kA = sh_k[0];
        prefB = sh_pref[1]; kB = sh_k[1];
        mask = 0xFFFFFFFFu << shift;
    }

    // ---- final: per-row sum of elements > t (+ k ties), and row max ----
    const unsigned int tA = prefA, tB = prefB;
    float sumA = 0.f, sumB = 0.f;
    unsigned int mA = 0u, mB = 0u;
    #pragma unroll
    for (int j = 0; j < 13; ++j) {
        const bool live = (j < 12) || has13;
        if (live) {
            mA = max(mA, u[j]);
            if (u[j] > tA) sumA += s2f(u[j]);
            mB = max(mB, w[j]);
            if (w[j] > tB) sumB += s2f(w[j]);
        }
    }
    #pragma unroll
    for (int off = 32; off > 0; off >>= 1) {
        sumA += __shfl_down(sumA, off);
        sumB += __shfl_down(sumB, off);
        mA = max(mA, __shfl_down(mA, off));
        mB = max(mB, __shfl_down(mB, off));
    }
    if (lane == 0) { redsA[wid] = sumA; redsB[wid] = sumB;
                     redmA[wid] = mA;   redmB[wid] = mB; }
    __syncthreads();
    if (tid == 0) {
        float totA = redsA[0] + redsA[1] + redsA[2] + redsA[3] + (float)kA * s2f(tA);
        float totB = redsB[0] + redsB[1] + redsB[2] + redsB[3] + (float)kB * s2f(tB);
        pool_avg[rowA]     = totA * (1.0f / (float)TOPT);
        pool_avg[rowA + 1] = totB * (1.0f / (float)TOPT);
        pool_max[rowA]     = s2f(max(max(redmA[0], redmA[1]), max(redmA[2], redmA[3])));
        pool_max[rowA + 1] = s2f(max(max(redmB[0], redmB[1]), max(redmB[2], redmB[3])));
    }
}

// ---------------- Kernel 2: channel-MLP + sigmoid -> s[b,c] --------------
// Layer 1 uses all 256 threads: 32 units x 2 pools x 4 K-segments of 128,
// partials combined via LDS (isolated win in R10: -4.4us vs 64-thread).
__global__ __launch_bounds__(256) void mlp_kernel(
        const float* __restrict__ pool_avg, const float* __restrict__ pool_max,
        const float* __restrict__ w1, const float* __restrict__ b1,
        const float* __restrict__ w2, const float* __restrict__ b2,
        float* __restrict__ s_out) {
    __shared__ float pa[NC], pm[NC], part[64][4], h1a[NR], h1m[NR];
    const int b = blockIdx.x, tid = threadIdx.x;
    for (int c = tid; c < NC; c += 256) {
        pa[c] = pool_avg[b * NC + c];
        pm[c] = pool_max[b * NC + c];
    }
    __syncthreads();
    {
        const int r = tid & 31;              // hidden unit
        const int half = (tid >> 5) & 1;     // 0=avg, 1=max
        const int seg = tid >> 6;            // K-segment 0..3
        const float* p = (half ? pm : pa) + seg * 128;
        const float* wrow = w1 + r * NC + seg * 128;
        float acc = 0.f;
        #pragma unroll 4
        for (int c = 0; c < 128; ++c) acc = fmaf(p[c], wrow[c], acc);
        part[tid & 63][seg] = acc;
    }
    __syncthreads();
    if (tid < 64) {
        const int r = tid & 31;
        float acc = b1[r] + part[tid][0] + part[tid][1]
                  + part[tid][2] + part[tid][3];
        float h = fmaxf(acc, 0.f);
        if (tid < 32) h1a[r] = h; else h1m[r] = h;
    }
    __syncthreads();
    for (int c = tid; c < NC; c += 256) {
        float acc = 2.f * b2[c];
        const float* wrow = w2 + c * NR;
        for (int r = 0; r < NR; ++r) acc += (h1a[r] + h1m[r]) * wrow[r];
        s_out[b * NC + c] = 1.f / (1.f + expf(-acc));
    }
}

// ---------------- Kernel 3: channel max/mean of x*s -> cp ----------------
__global__ __launch_bounds__(256) void spatial_pool_kernel(
        const float* __restrict__ x, const float* __restrict__ s,
        float* __restrict__ cp_max, float* __restrict__ cp_avg) {
    __shared__ float sc[NC];
    __shared__ float4 pmx[7][32];
    __shared__ float4 psm[7][32];
    const int b = blockIdx.y, tid = threadIdx.x;
    const int qo = tid & 31;                 // float4-pixel within tile
    const int cg = tid >> 5;                 // channel group 0..7
    const int q = blockIdx.x * 32 + qo;      // float4 index, 0..783 valid
    for (int c = tid; c < NC; c += 256) sc[c] = s[b * NC + c];
    __syncthreads();
    const float4* xb4 = (const float4*)(x + (size_t)b * NC * NHW);
    float4 mx = make_float4(-INFINITY, -INFINITY, -INFINITY, -INFINITY);
    float4 sm = make_float4(0.f, 0.f, 0.f, 0.f);
    const bool valid = (q < NHW / 4);
    if (valid) {
        #pragma unroll 2
        for (int c = cg * 64; c < cg * 64 + 64; ++c) {
            float4 v = xb4[(size_t)c * (NHW / 4) + q];
            const float scv = sc[c];
            v.x *= scv; v.y *= scv; v.z *= scv; v.w *= scv;
            mx.x = fmaxf(mx.x, v.x); mx.y = fmaxf(mx.y, v.y);
            mx.z = fmaxf(mx.z, v.z); mx.w = fmaxf(mx.w, v.w);
            sm.x += v.x; sm.y += v.y; sm.z += v.z; sm.w += v.w;
        }
    }
    if (cg > 0 && valid) { pmx[cg - 1][qo] = mx; psm[cg - 1][qo] = sm; }
    __syncthreads();
    if (cg == 0 && valid) {
        #pragma unroll
        for (int i = 0; i < 7; ++i) {
            const float4 m2 = pmx[i][qo];
            const float4 s2 = psm[i][qo];
            mx.x = fmaxf(mx.x, m2.x); mx.y = fmaxf(mx.y, m2.y);
            mx.z = fmaxf(mx.z, m2.z); mx.w = fmaxf(mx.w, m2.w);
            sm.x += s2.x; sm.y += s2.y; sm.z += s2.z; sm.w += s2.w;
        }
        const float inv = 1.0f / (float)NC;
        sm.x *= inv; sm.y *= inv; sm.z *= inv; sm.w *= inv;
        ((float4*)(cp_max + b * NHW))[q] = mx;
        ((float4*)(cp_avg + b * NHW))[q] = sm;
    }
}

// ---------------- Kernel 4: 7x7 conv + BN + sigmoid -> g[b,hw] -----------
__global__ __launch_bounds__(256) void conv_gate_kernel(
        const float* __restrict__ cp_max, const float* __restrict__ cp_avg,
        const float* __restrict__ conv_w,
        const float* __restrict__ gamma, const float* __restrict__ beta,
        const float* __restrict__ mean, const float* __restrict__ var,
        float* __restrict__ g) {
    __shared__ float wgt[98];
    const int b = blockIdx.y, tid = threadIdx.x;
    const int p = blockIdx.x * 256 + tid;
    if (tid < 98) wgt[tid] = conv_w[tid];
    __syncthreads();
    if (p >= NHW) return;
    const int h = p / NW, w = p - h * NW;
    const float* cm = cp_max + b * NHW;
    const float* ca = cp_avg + b * NHW;
    float acc = 0.f;
    for (int i = 0; i < 7; ++i) {
        const int hh = h - 3 + i;
        if (hh < 0 || hh >= NH) continue;
        for (int j = 0; j < 7; ++j) {
            const int ww = w - 3 + j;
            if (ww < 0 || ww >= NW) continue;
            const int q = hh * NW + ww;
            acc += cm[q] * wgt[i * 7 + j] + ca[q] * wgt[49 + i * 7 + j];
        }
    }
    const float bnv = (acc - mean[0]) * rsqrtf(var[0] + 1e-5f) * gamma[0] + beta[0];
    g[b * NHW + p] = 1.f / (1.f + expf(-bnv));
}

// ---------------- Kernel 5: out = x * s[b,c] * g[b,hw] -------------------
// One block per (b,c) row: scalar s broadcast, nontemporal stores so the
// 205 MB output stream doesn't evict x from L3.
__global__ __launch_bounds__(256) void scale_out_kernel(
        const float* __restrict__ x, const float* __restrict__ s,
        const float* __restrict__ g, float* __restrict__ out) {
    const int bc = blockIdx.x;               // 0..16383
    const int b = bc >> 9;
    const int tid = threadIdx.x;
    const float sv = s[bc];
    const f32x4* xr = (const f32x4*)(x + (size_t)bc * NHW);
    const f32x4* gr = (const f32x4*)(g + (size_t)b * NHW);
    f32x4* orow = (f32x4*)(out + (size_t)bc * NHW);
    #pragma unroll
    for (int i = 0; i < 3; ++i) {            // 3*256 = 768 of 784 float4s
        const int q = tid + 256 * i;
        f32x4 xv = xr[q];
        f32x4 gv = gr[q];
        f32x4 ov = xv * sv * gv;
        __builtin_nontemporal_store(ov, &orow[q]);
    }
    if (tid < 16) {                          // tail: 768..783
        const int q = 768 + tid;
        f32x4 xv = xr[q];
        f32x4 gv = gr[q];
        f32x4 ov = xv * sv * gv;
        __builtin_nontemporal_store(ov, &orow[q]);
    }
}

extern "C" void kernel_launch(void* const* d_in, const int* in_sizes, int n_in,
                              void* d_out, int out_size, void* d_ws, size_t ws_size,
                              hipStream_t stream) {
    const float* x      = (const float*)d_in[0];
    const float* w1     = (const float*)d_in[1];
    const float* b1     = (const float*)d_in[2];
    const float* w2     = (const float*)d_in[3];
    const float* b2     = (const float*)d_in[4];
    const float* conv_w = (const float*)d_in[5];
    const float* gamma  = (const float*)d_in[6];
    const float* beta   = (const float*)d_in[7];
    const float* mean   = (const float*)d_in[8];
    const float* var    = (const float*)d_in[9];
    float* out = (float*)d_out;

    float* ws = (float*)d_ws;
    float* pool_avg = ws;                       // 16384
    float* pool_max = ws + 16384;               // 16384
    float* s        = ws + 32768;               // 16384
    float* cp_max   = ws + 49152;               // 100352
    float* cp_avg   = ws + 149504;              // 100352
    float* g        = ws + 249856;              // 100352  (total 1.37 MB)

    topk_pool_kernel<<<NB * NC / 2, 256, 0, stream>>>(x, pool_avg, pool_max);
    mlp_kernel<<<NB, 256, 0, stream>>>(pool_avg, pool_max, w1, b1, w2, b2, s);
    dim3 grid3((NHW / 4 + 31) / 32, NB);        // (25, 32) = 800 blocks
    spatial_pool_kernel<<<grid3, 256, 0, stream>>>(x, s, cp_max, cp_avg);
    dim3 grid4((NHW + 255) / 256, NB);
    conv_gate_kernel<<<grid4, 256, 0, stream>>>(cp_max, cp_avg, conv_w,
                                                gamma, beta, mean, var, g);
    scale_out_kernel<<<NB * NC, 256, 0, stream>>>(x, s, g, out);
}

// Round 12
// 170.456 us; speedup vs baseline: 1.0915x; 1.0012x over previous
//
#include <hip/hip_runtime.h>
#include <math.h>

// Problem constants (B,C,H,W = 32,512,56,56; top_t = round(3136*0.1) = 314)
#define NB 32
#define NC 512
#define NH 56
#define NW 56
#define NHW 3136
#define TOPT 314
#define NR 32
#define RBUCK 2048

typedef float f32x4 __attribute__((ext_vector_type(4)));

__device__ __forceinline__ unsigned int f2s(float f) {
    unsigned int b = __float_as_uint(f);
    return (b & 0x80000000u) ? ~b : (b | 0x80000000u);
}
__device__ __forceinline__ float s2f(unsigned int u) {
    unsigned int b = (u & 0x80000000u) ? (u ^ 0x80000000u) : ~u;
    return __uint_as_float(b);
}

// ---------------- Kernel 1: exact top-314 sum + max, TWO rows/block ------
// R11 skeleton (measured best) + ONE change: the 24 main row values are
// PINNED into VGPRs via opaque no-op asm. Rationale: VGPR_Count=20 proves
// the compiler was re-loading x from cache for every radix round and the
// final pass (26 live values can't fit in 20 regs; const __restrict__
// loads are freely rematerializable) -> ~4x205 MB of hidden L2/L3 read
// traffic per dispatch. Pinning makes the loaded values opaque asm
// outputs, which cannot be rematerialized -> single read of x.
// 24 pins + working set stays <= 64 VGPR -> still 8 waves/SIMD.
// Rows 2*blk and 2*blk+1 share one SWAR-packed histogram: row A counts in
// bits[15:0], row B in bits[31:16]. Round-0 atomics split across two
// histogram copies by lane parity (R11, -1.8us). 3-round 11-bit radix
// select; packed suffix scan finds each row's threshold bucket; exact tie
// handling via k*val(t).
__global__ __launch_bounds__(256) void topk_pool_kernel(
        const float* __restrict__ x,
        float* __restrict__ pool_avg, float* __restrict__ pool_max) {
    __shared__ unsigned int hist[2][RBUCK];      // 16 KB
    __shared__ unsigned int wtot[4];
    __shared__ unsigned int sh_pref[2], sh_k[2];
    __shared__ float redsA[4], redsB[4];
    __shared__ unsigned int redmA[4], redmB[4];

    const int rowA = blockIdx.x * 2;
    const int tid = threadIdx.x;
    const int wid = tid >> 6;
    const int lane = tid & 63;
    const float* xa = x + (size_t)rowA * NHW;
    const float* xb = xa + NHW;
    const float4* xa4 = (const float4*)xa;
    const float4* xb4 = (const float4*)xb;

    // 3136 = 12*256 + 64: three float4 loads + one scalar (tid<64), per row
    float4 a0 = xa4[tid], a1 = xa4[256 + tid], a2 = xa4[512 + tid];
    float4 b0 = xb4[tid], b1 = xb4[256 + tid], b2 = xb4[512 + tid];
    const bool has13 = (tid < 64);
    float exA = has13 ? xa[3072 + tid] : 0.f;
    float exB = has13 ? xb[3072 + tid] : 0.f;

    unsigned int u[13], w[13];
    u[0] = f2s(a0.x); u[1] = f2s(a0.y); u[2]  = f2s(a0.z); u[3]  = f2s(a0.w);
    u[4] = f2s(a1.x); u[5] = f2s(a1.y); u[6]  = f2s(a1.z); u[7]  = f2s(a1.w);
    u[8] = f2s(a2.x); u[9] = f2s(a2.y); u[10] = f2s(a2.z); u[11] = f2s(a2.w);
    u[12] = f2s(exA);
    w[0] = f2s(b0.x); w[1] = f2s(b0.y); w[2]  = f2s(b0.z); w[3]  = f2s(b0.w);
    w[4] = f2s(b1.x); w[5] = f2s(b1.y); w[6]  = f2s(b1.z); w[7]  = f2s(b1.w);
    w[8] = f2s(b2.x); w[9] = f2s(b2.y); w[10] = f2s(b2.z); w[11] = f2s(b2.w);
    w[12] = f2s(exB);

    // Pin the 24 main values: opaque asm output can't be rematerialized
    // from the global load, so these stay register-resident across all
    // rounds (tail u[12]/w[12] left unpinned to stay under the 64-VGPR
    // occupancy cliff; their re-load is 1 scalar for 64 threads).
    #pragma unroll
    for (int j = 0; j < 12; ++j) {
        asm volatile("" : "+v"(u[j]));
        asm volatile("" : "+v"(w[j]));
    }

    unsigned int prefA = 0u, prefB = 0u, mask = 0u;
    unsigned int kA = TOPT, kB = TOPT;
    const int shifts[3] = {21, 10, 0};
    #pragma unroll
    for (int r = 0; r < 3; ++r) {
        const int shift = shifts[r];
        {   // zero histogram(s)
            uint4 z = make_uint4(0u, 0u, 0u, 0u);
            uint4* h0 = (uint4*)hist[0];
            h0[tid] = z; h0[256 + tid] = z;
            if (r == 0) {
                uint4* h1 = (uint4*)hist[1];
                h1[tid] = z; h1[256 + tid] = z;
            }
        }
        __syncthreads();
        // round 0: split same-bucket atomics across two copies by lane
        // parity; rounds 1-2: single bank (few survivors)
        unsigned int* h = (r == 0) ? hist[lane & 1] : hist[0];
        #pragma unroll
        for (int j = 0; j < 13; ++j) {
            const bool live = (j < 12) || has13;
            if (live && ((u[j] & mask) == prefA))
                atomicAdd(&h[(u[j] >> shift) & (RBUCK - 1u)], 1u);
            if (live && ((w[j] & mask) == prefB))
                atomicAdd(&h[(w[j] >> shift) & (RBUCK - 1u)], 65536u);
        }
        __syncthreads();

        // fold 8 buckets/thread into registers (packed counts)
        unsigned int vv[8];
        unsigned int g = 0u;
        if (r == 0) {
            #pragma unroll
            for (int bb = 0; bb < 8; ++bb) {
                vv[bb] = hist[0][8 * tid + bb] + hist[1][8 * tid + bb];
                g += vv[bb];
            }
        } else {
            #pragma unroll
            for (int bb = 0; bb < 8; ++bb) { vv[bb] = hist[0][8 * tid + bb]; g += vv[bb]; }
        }
        // packed suffix-inclusive scan over threads
        unsigned int S = g;
        #pragma unroll
        for (int off = 1; off < 64; off <<= 1) {
            unsigned int t2 = __shfl_down(S, off);
            if (lane + off < 64) S += t2;
        }
        if (lane == 0) wtot[wid] = S;
        __syncthreads();
        unsigned int hi = 0u;
        if (wid < 3) hi += wtot[wid + 1];
        if (wid < 2) hi += wtot[wid + 2];
        if (wid < 1) hi += wtot[wid + 3];
        S += hi;                               // packed: count in buckets >= mine
        const unsigned int SloT = S & 0xFFFFu, ShiT = S >> 16;
        const unsigned int gLo = g & 0xFFFFu,  gHi = g >> 16;
        const unsigned int aboveLo = SloT - gLo, aboveHi = ShiT - gHi;
        if (SloT >= kA && aboveLo < kA) {      // unique crossing thread, row A
            unsigned int cum = aboveLo;
            #pragma unroll
            for (int bb = 7; bb >= 0; --bb) {
                const unsigned int hh = vv[bb] & 0xFFFFu;
                if (cum + hh >= kA) {
                    sh_pref[0] = prefA | ((unsigned int)(8 * tid + bb) << shift);
                    sh_k[0] = kA - cum;
                    break;
                }
                cum += hh;
            }
        }
        if (ShiT >= kB && aboveHi < kB) {      // row B
            unsigned int cum = aboveHi;
            #pragma unroll
            for (int bb = 7; bb >= 0; --bb) {
                const unsigned int hh = vv[bb] >> 16;
                if (cum + hh >= kB) {
                    sh_pref[1] = prefB | ((unsigned int)(8 * tid + bb) << shift);
                    sh_k[1] = kB - cum;
                    break;
                }
                cum += hh;
            }
        }
        __syncthreads();
        prefA = sh_pref[0]; kA = sh_k[0];
        prefB = sh_pref[1]; kB = sh_k[1];
        mask = 0xFFFFFFFFu << shift;
    }

    // ---- final: per-row sum of elements > t (+ k ties), and row max ----
    const unsigned int tA = prefA, tB = prefB;
    float sumA = 0.f, sumB = 0.f;
    unsigned int mA = 0u, mB = 0u;
    #pragma unroll
    for (int j = 0; j < 13; ++j) {
        const bool live = (j < 12) || has13;
        if (live) {
            mA = max(mA, u[j]);
            if (u[j] > tA) sumA += s2f(u[j]);
            mB = max(mB, w[j]);
            if (w[j] > tB) sumB += s2f(w[j]);
        }
    }
    #pragma unroll
    for (int off = 32; off > 0; off >>= 1) {
        sumA += __shfl_down(sumA, off);
        sumB += __shfl_down(sumB, off);
        mA = max(mA, __shfl_down(mA, off));
        mB = max(mB, __shfl_down(mB, off));
    }
    if (lane == 0) { redsA[wid] = sumA; redsB[wid] = sumB;
                     redmA[wid] = mA;   redmB[wid] = mB; }
    __syncthreads();
    if (tid == 0) {
        float totA = redsA[0] + redsA[1] + redsA[2] + redsA[3] + (float)kA * s2f(tA);
        float totB = redsB[0] + redsB[1] + redsB[2] + redsB[3] + (float)kB * s2f(tB);
        pool_avg[rowA]     = totA * (1.0f / (float)TOPT);
        pool_avg[rowA + 1] = totB * (1.0f / (float)TOPT);
        pool_max[rowA]     = s2f(max(max(redmA[0], redmA[1]), max(redmA[2], redmA[3])));
        pool_max[rowA + 1] = s2f(max(max(redmB[0], redmB[1]), max(redmB[2], redmB[3])));
    }
}

// ---------------- Kernel 2: channel-MLP + sigmoid -> s[b,c] --------------
// Layer 1 uses all 256 threads: 32 units x 2 pools x 4 K-segments of 128,
// partials combined via LDS (isolated win in R10: -4.4us vs 64-thread).
__global__ __launch_bounds__(256) void mlp_kernel(
        const float* __restrict__ pool_avg, const float* __restrict__ pool_max,
        const float* __restrict__ w1, const float* __restrict__ b1,
        const float* __restrict__ w2, const float* __restrict__ b2,
        float* __restrict__ s_out) {
    __shared__ float pa[NC], pm[NC], part[64][4], h1a[NR], h1m[NR];
    const int b = blockIdx.x, tid = threadIdx.x;
    for (int c = tid; c < NC; c += 256) {
        pa[c] = pool_avg[b * NC + c];
        pm[c] = pool_max[b * NC + c];
    }
    __syncthreads();
    {
        const int r = tid & 31;              // hidden unit
        const int half = (tid >> 5) & 1;     // 0=avg, 1=max
        const int seg = tid >> 6;            // K-segment 0..3
        const float* p = (half ? pm : pa) + seg * 128;
        const float* wrow = w1 + r * NC + seg * 128;
        float acc = 0.f;
        #pragma unroll 4
        for (int c = 0; c < 128; ++c) acc = fmaf(p[c], wrow[c], acc);
        part[tid & 63][seg] = acc;
    }
    __syncthreads();
    if (tid < 64) {
        const int r = tid & 31;
        float acc = b1[r] + part[tid][0] + part[tid][1]
                  + part[tid][2] + part[tid][3];
        float h = fmaxf(acc, 0.f);
        if (tid < 32) h1a[r] = h; else h1m[r] = h;
    }
    __syncthreads();
    for (int c = tid; c < NC; c += 256) {
        float acc = 2.f * b2[c];
        const float* wrow = w2 + c * NR;
        for (int r = 0; r < NR; ++r) acc += (h1a[r] + h1m[r]) * wrow[r];
        s_out[b * NC + c] = 1.f / (1.f + expf(-acc));
    }
}

// ---------------- Kernel 3: channel max/mean of x*s -> cp ----------------
__global__ __launch_bounds__(256) void spatial_pool_kernel(
        const float* __restrict__ x, const float* __restrict__ s,
        float* __restrict__ cp_max, float* __restrict__ cp_avg) {
    __shared__ float sc[NC];
    __shared__ float4 pmx[7][32];
    __shared__ float4 psm[7][32];
    const int b = blockIdx.y, tid = threadIdx.x;
    const int qo = tid & 31;                 // float4-pixel within tile
    const int cg = tid >> 5;                 // channel group 0..7
    const int q = blockIdx.x * 32 + qo;      // float4 index, 0..783 valid
    for (int c = tid; c < NC; c += 256) sc[c] = s[b * NC + c];
    __syncthreads();
    const float4* xb4 = (const float4*)(x + (size_t)b * NC * NHW);
    float4 mx = make_float4(-INFINITY, -INFINITY, -INFINITY, -INFINITY);
    float4 sm = make_float4(0.f, 0.f, 0.f, 0.f);
    const bool valid = (q < NHW / 4);
    if (valid) {
        #pragma unroll 2
        for (int c = cg * 64; c < cg * 64 + 64; ++c) {
            float4 v = xb4[(size_t)c * (NHW / 4) + q];
            const float scv = sc[c];
            v.x *= scv; v.y *= scv; v.z *= scv; v.w *= scv;
            mx.x = fmaxf(mx.x, v.x); mx.y = fmaxf(mx.y, v.y);
            mx.z = fmaxf(mx.z, v.z); mx.w = fmaxf(mx.w, v.w);
            sm.x += v.x; sm.y += v.y; sm.z += v.z; sm.w += v.w;
        }
    }
    if (cg > 0 && valid) { pmx[cg - 1][qo] = mx; psm[cg - 1][qo] = sm; }
    __syncthreads();
    if (cg == 0 && valid) {
        #pragma unroll
        for (int i = 0; i < 7; ++i) {
            const float4 m2 = pmx[i][qo];
            const float4 s2 = psm[i][qo];
            mx.x = fmaxf(mx.x, m2.x); mx.y = fmaxf(mx.y, m2.y);
            mx.z = fmaxf(mx.z, m2.z); mx.w = fmaxf(mx.w, m2.w);
            sm.x += s2.x; sm.y += s2.y; sm.z += s2.z; sm.w += s2.w;
        }
        const float inv = 1.0f / (float)NC;
        sm.x *= inv; sm.y *= inv; sm.z *= inv; sm.w *= inv;
        ((float4*)(cp_max + b * NHW))[q] = mx;
        ((float4*)(cp_avg + b * NHW))[q] = sm;
    }
}

// ---------------- Kernel 4: 7x7 conv + BN + sigmoid -> g[b,hw] -----------
__global__ __launch_bounds__(256) void conv_gate_kernel(
        const float* __restrict__ cp_max, const float* __restrict__ cp_avg,
        const float* __restrict__ conv_w,
        const float* __restrict__ gamma, const float* __restrict__ beta,
        const float* __restrict__ mean, const float* __restrict__ var,
        float* __restrict__ g) {
    __shared__ float wgt[98];
    const int b = blockIdx.y, tid = threadIdx.x;
    const int p = blockIdx.x * 256 + tid;
    if (tid < 98) wgt[tid] = conv_w[tid];
    __syncthreads();
    if (p >= NHW) return;
    const int h = p / NW, w = p - h * NW;
    const float* cm = cp_max + b * NHW;
    const float* ca = cp_avg + b * NHW;
    float acc = 0.f;
    for (int i = 0; i < 7; ++i) {
        const int hh = h - 3 + i;
        if (hh < 0 || hh >= NH) continue;
        for (int j = 0; j < 7; ++j) {
            const int ww = w - 3 + j;
            if (ww < 0 || ww >= NW) continue;
            const int q = hh * NW + ww;
            acc += cm[q] * wgt[i * 7 + j] + ca[q] * wgt[49 + i * 7 + j];
        }
    }
    const float bnv = (acc - mean[0]) * rsqrtf(var[0] + 1e-5f) * gamma[0] + beta[0];
    g[b * NHW + p] = 1.f / (1.f + expf(-bnv));
}

// ---------------- Kernel 5: out = x * s[b,c] * g[b,hw] -------------------
// One block per (b,c) row: scalar s broadcast, nontemporal stores so the
// 205 MB output stream doesn't evict x from L3.
__global__ __launch_bounds__(256) void scale_out_kernel(
        const float* __restrict__ x, const float* __restrict__ s,
        const float* __restrict__ g, float* __restrict__ out) {
    const int bc = blockIdx.x;               // 0..16383
    const int b = bc >> 9;
    const int tid = threadIdx.x;
    const float sv = s[bc];
    const f32x4* xr = (const f32x4*)(x + (size_t)bc * NHW);
    const f32x4* gr = (const f32x4*)(g + (size_t)b * NHW);
    f32x4* orow = (f32x4*)(out + (size_t)bc * NHW);
    #pragma unroll
    for (int i = 0; i < 3; ++i) {            // 3*256 = 768 of 784 float4s
        const int q = tid + 256 * i;
        f32x4 xv = xr[q];
        f32x4 gv = gr[q];
        f32x4 ov = xv * sv * gv;
        __builtin_nontemporal_store(ov, &orow[q]);
    }
    if (tid < 16) {                          // tail: 768..783
        const int q = 768 + tid;
        f32x4 xv = xr[q];
        f32x4 gv = gr[q];
        f32x4 ov = xv * sv * gv;
        __builtin_nontemporal_store(ov, &orow[q]);
    }
}

extern "C" void kernel_launch(void* const* d_in, const int* in_sizes, int n_in,
                              void* d_out, int out_size, void* d_ws, size_t ws_size,
                              hipStream_t stream) {
    const float* x      = (const float*)d_in[0];
    const float* w1     = (const float*)d_in[1];
    const float* b1     = (const float*)d_in[2];
    const float* w2     = (const float*)d_in[3];
    const float* b2     = (const float*)d_in[4];
    const float* conv_w = (const float*)d_in[5];
    const float* gamma  = (const float*)d_in[6];
    const float* beta   = (const float*)d_in[7];
    const float* mean   = (const float*)d_in[8];
    const float* var    = (const float*)d_in[9];
    float* out = (float*)d_out;

    float* ws = (float*)d_ws;
    float* pool_avg = ws;                       // 16384
    float* pool_max = ws + 16384;               // 16384
    float* s        = ws + 32768;               // 16384
    float* cp_max   = ws + 49152;               // 100352
    float* cp_avg   = ws + 149504;              // 100352
    float* g        = ws + 249856;              // 100352  (total 1.37 MB)

    topk_pool_kernel<<<NB * NC / 2, 256, 0, stream>>>(x, pool_avg, pool_max);
    mlp_kernel<<<NB, 256, 0, stream>>>(pool_avg, pool_max, w1, b1, w2, b2, s);
    dim3 grid3((NHW / 4 + 31) / 32, NB);        // (25, 32) = 800 blocks
    spatial_pool_kernel<<<grid3, 256, 0, stream>>>(x, s, cp_max, cp_avg);
    dim3 grid4((NHW + 255) / 256, NB);
    conv_gate_kernel<<<grid4, 256, 0, stream>>>(cp_max, cp_avg, conv_w,
                                                gamma, beta, mean, var, g);
    scale_out_kernel<<<NB * NC, 256, 0, stream>>>(x, s, g, out);
}

// Round 13
// 163.154 us; speedup vs baseline: 1.1403x; 1.0448x over previous
//
#include <hip/hip_runtime.h>
#include <math.h>

// Problem constants (B,C,H,W = 32,512,56,56; top_t = round(3136*0.1) = 314)
#define NB 32
#define NC 512
#define NH 56
#define NW 56
#define NHW 3136
#define TOPT 314
#define NR 32
#define RBUCK 2048

typedef float f32x4 __attribute__((ext_vector_type(4)));

__device__ __forceinline__ unsigned int f2s(float f) {
    unsigned int b = __float_as_uint(f);
    return (b & 0x80000000u) ? ~b : (b | 0x80000000u);
}
__device__ __forceinline__ float s2f(unsigned int u) {
    unsigned int b = (u & 0x80000000u) ? (u ^ 0x80000000u) : ~u;
    return __uint_as_float(b);
}

// ---------------- Kernel 1: exact top-314 sum + max, TWO rows/block ------
// R11/R12 skeleton + ONE change: ROUND 2 IS SKIPPED when provably a no-op.
// After round 1 (22 bits resolved), if the crossing search finds that ALL
// c elements of the threshold bucket are in the top-k (k'' == c — true
// whenever c==1, ~94% of blocks for 122 survivors over 2048 buckets),
// then the top-314 set is exactly {u >= pref22}: count = above + c = 314.
// The final pass then sums u >= pref with NO tie term. Exact: the skip
// condition is checked per row from exact counts; both-rows-qualify is a
// block-uniform branch; the 6% remainder run round 2 unchanged.
// Rows 2*blk and 2*blk+1 share one SWAR-packed histogram: row A counts in
// bits[15:0], row B in bits[31:16]. Round-0 atomics split across two
// histogram copies by lane parity (R11). 3-round 11-bit radix select;
// packed suffix scan finds each row's threshold bucket.
__global__ __launch_bounds__(256) void topk_pool_kernel(
        const float* __restrict__ x,
        float* __restrict__ pool_avg, float* __restrict__ pool_max) {
    __shared__ unsigned int hist[2][RBUCK];      // 16 KB
    __shared__ unsigned int wtot[4];
    __shared__ unsigned int sh_pref[2], sh_k[2], sh_cnt[2];
    __shared__ float redsA[4], redsB[4];
    __shared__ unsigned int redmA[4], redmB[4];

    const int rowA = blockIdx.x * 2;
    const int tid = threadIdx.x;
    const int wid = tid >> 6;
    const int lane = tid & 63;
    const float* xa = x + (size_t)rowA * NHW;
    const float* xb = xa + NHW;
    const float4* xa4 = (const float4*)xa;
    const float4* xb4 = (const float4*)xb;

    // 3136 = 12*256 + 64: three float4 loads + one scalar (tid<64), per row
    float4 a0 = xa4[tid], a1 = xa4[256 + tid], a2 = xa4[512 + tid];
    float4 b0 = xb4[tid], b1 = xb4[256 + tid], b2 = xb4[512 + tid];
    const bool has13 = (tid < 64);
    float exA = has13 ? xa[3072 + tid] : 0.f;
    float exB = has13 ? xb[3072 + tid] : 0.f;

    unsigned int u[13], w[13];
    u[0] = f2s(a0.x); u[1] = f2s(a0.y); u[2]  = f2s(a0.z); u[3]  = f2s(a0.w);
    u[4] = f2s(a1.x); u[5] = f2s(a1.y); u[6]  = f2s(a1.z); u[7]  = f2s(a1.w);
    u[8] = f2s(a2.x); u[9] = f2s(a2.y); u[10] = f2s(a2.z); u[11] = f2s(a2.w);
    u[12] = f2s(exA);
    w[0] = f2s(b0.x); w[1] = f2s(b0.y); w[2]  = f2s(b0.z); w[3]  = f2s(b0.w);
    w[4] = f2s(b1.x); w[5] = f2s(b1.y); w[6]  = f2s(b1.z); w[7]  = f2s(b1.w);
    w[8] = f2s(b2.x); w[9] = f2s(b2.y); w[10] = f2s(b2.z); w[11] = f2s(b2.w);
    w[12] = f2s(exB);

    #pragma unroll
    for (int j = 0; j < 12; ++j) {
        asm volatile("" : "+v"(u[j]));
        asm volatile("" : "+v"(w[j]));
    }

    unsigned int prefA = 0u, prefB = 0u, mask = 0u;
    unsigned int kA = TOPT, kB = TOPT;
    bool skip2 = false;
    const int shifts[3] = {21, 10, 0};
    #pragma unroll
    for (int r = 0; r < 3; ++r) {
        if (r == 2 && skip2) break;          // round 2 provably a no-op
        const int shift = shifts[r];
        {   // zero histogram(s)
            uint4 z = make_uint4(0u, 0u, 0u, 0u);
            uint4* h0 = (uint4*)hist[0];
            h0[tid] = z; h0[256 + tid] = z;
            if (r == 0) {
                uint4* h1 = (uint4*)hist[1];
                h1[tid] = z; h1[256 + tid] = z;
            }
        }
        __syncthreads();
        // round 0: split same-bucket atomics across two copies by lane
        // parity; rounds 1-2: single bank (few survivors)
        unsigned int* h = (r == 0) ? hist[lane & 1] : hist[0];
        #pragma unroll
        for (int j = 0; j < 13; ++j) {
            const bool live = (j < 12) || has13;
            if (live && ((u[j] & mask) == prefA))
                atomicAdd(&h[(u[j] >> shift) & (RBUCK - 1u)], 1u);
            if (live && ((w[j] & mask) == prefB))
                atomicAdd(&h[(w[j] >> shift) & (RBUCK - 1u)], 65536u);
        }
        __syncthreads();

        // fold 8 buckets/thread into registers (packed counts)
        unsigned int vv[8];
        unsigned int g = 0u;
        if (r == 0) {
            #pragma unroll
            for (int bb = 0; bb < 8; ++bb) {
                vv[bb] = hist[0][8 * tid + bb] + hist[1][8 * tid + bb];
                g += vv[bb];
            }
        } else {
            #pragma unroll
            for (int bb = 0; bb < 8; ++bb) { vv[bb] = hist[0][8 * tid + bb]; g += vv[bb]; }
        }
        // packed suffix-inclusive scan over threads
        unsigned int S = g;
        #pragma unroll
        for (int off = 1; off < 64; off <<= 1) {
            unsigned int t2 = __shfl_down(S, off);
            if (lane + off < 64) S += t2;
        }
        if (lane == 0) wtot[wid] = S;
        __syncthreads();
        unsigned int hi = 0u;
        if (wid < 3) hi += wtot[wid + 1];
        if (wid < 2) hi += wtot[wid + 2];
        if (wid < 1) hi += wtot[wid + 3];
        S += hi;                               // packed: count in buckets >= mine
        const unsigned int SloT = S & 0xFFFFu, ShiT = S >> 16;
        const unsigned int gLo = g & 0xFFFFu,  gHi = g >> 16;
        const unsigned int aboveLo = SloT - gLo, aboveHi = ShiT - gHi;
        if (SloT >= kA && aboveLo < kA) {      // unique crossing thread, row A
            unsigned int cum = aboveLo;
            #pragma unroll
            for (int bb = 7; bb >= 0; --bb) {
                const unsigned int hh = vv[bb] & 0xFFFFu;
                if (cum + hh >= kA) {
                    sh_pref[0] = prefA | ((unsigned int)(8 * tid + bb) << shift);
                    sh_k[0] = kA - cum;
                    if (r == 1) sh_cnt[0] = hh;  // bucket count c for skip test
                    break;
                }
                cum += hh;
            }
        }
        if (ShiT >= kB && aboveHi < kB) {      // row B
            unsigned int cum = aboveHi;
            #pragma unroll
            for (int bb = 7; bb >= 0; --bb) {
                const unsigned int hh = vv[bb] >> 16;
                if (cum + hh >= kB) {
                    sh_pref[1] = prefB | ((unsigned int)(8 * tid + bb) << shift);
                    sh_k[1] = kB - cum;
                    if (r == 1) sh_cnt[1] = hh;
                    break;
                }
                cum += hh;
            }
        }
        __syncthreads();
        prefA = sh_pref[0]; kA = sh_k[0];
        prefB = sh_pref[1]; kB = sh_k[1];
        if (r == 1) skip2 = (kA == sh_cnt[0]) && (kB == sh_cnt[1]);
        mask = 0xFFFFFFFFu << shift;
    }

    // ---- final: per-row sum of top-314 (+ ties), and row max ----
    const unsigned int tA = prefA, tB = prefB;
    float sumA = 0.f, sumB = 0.f;
    unsigned int mA = 0u, mB = 0u;
    if (skip2) {
        // top-314 set is exactly {u >= pref22}; no tie correction needed
        #pragma unroll
        for (int j = 0; j < 13; ++j) {
            const bool live = (j < 12) || has13;
            if (live) {
                mA = max(mA, u[j]);
                if (u[j] >= tA) sumA += s2f(u[j]);
                mB = max(mB, w[j]);
                if (w[j] >= tB) sumB += s2f(w[j]);
            }
        }
    } else {
        #pragma unroll
        for (int j = 0; j < 13; ++j) {
            const bool live = (j < 12) || has13;
            if (live) {
                mA = max(mA, u[j]);
                if (u[j] > tA) sumA += s2f(u[j]);
                mB = max(mB, w[j]);
                if (w[j] > tB) sumB += s2f(w[j]);
            }
        }
    }
    #pragma unroll
    for (int off = 32; off > 0; off >>= 1) {
        sumA += __shfl_down(sumA, off);
        sumB += __shfl_down(sumB, off);
        mA = max(mA, __shfl_down(mA, off));
        mB = max(mB, __shfl_down(mB, off));
    }
    if (lane == 0) { redsA[wid] = sumA; redsB[wid] = sumB;
                     redmA[wid] = mA;   redmB[wid] = mB; }
    __syncthreads();
    if (tid == 0) {
        const float tieA = skip2 ? 0.f : (float)kA * s2f(tA);
        const float tieB = skip2 ? 0.f : (float)kB * s2f(tB);
        float totA = redsA[0] + redsA[1] + redsA[2] + redsA[3] + tieA;
        float totB = redsB[0] + redsB[1] + redsB[2] + redsB[3] + tieB;
        pool_avg[rowA]     = totA * (1.0f / (float)TOPT);
        pool_avg[rowA + 1] = totB * (1.0f / (float)TOPT);
        pool_max[rowA]     = s2f(max(max(redmA[0], redmA[1]), max(redmA[2], redmA[3])));
        pool_max[rowA + 1] = s2f(max(max(redmB[0], redmB[1]), max(redmB[2], redmB[3])));
    }
}

// ---------------- Kernel 2: channel-MLP + sigmoid -> s[b,c] --------------
// Layer 1 uses all 256 threads: 32 units x 2 pools x 4 K-segments of 128,
// partials combined via LDS (isolated win in R10: -4.4us vs 64-thread).
__global__ __launch_bounds__(256) void mlp_kernel(
        const float* __restrict__ pool_avg, const float* __restrict__ pool_max,
        const float* __restrict__ w1, const float* __restrict__ b1,
        const float* __restrict__ w2, const float* __restrict__ b2,
        float* __restrict__ s_out) {
    __shared__ float pa[NC], pm[NC], part[64][4], h1a[NR], h1m[NR];
    const int b = blockIdx.x, tid = threadIdx.x;
    for (int c = tid; c < NC; c += 256) {
        pa[c] = pool_avg[b * NC + c];
        pm[c] = pool_max[b * NC + c];
    }
    __syncthreads();
    {
        const int r = tid & 31;              // hidden unit
        const int half = (tid >> 5) & 1;     // 0=avg, 1=max
        const int seg = tid >> 6;            // K-segment 0..3
        const float* p = (half ? pm : pa) + seg * 128;
        const float* wrow = w1 + r * NC + seg * 128;
        float acc = 0.f;
        #pragma unroll 4
        for (int c = 0; c < 128; ++c) acc = fmaf(p[c], wrow[c], acc);
        part[tid & 63][seg] = acc;
    }
    __syncthreads();
    if (tid < 64) {
        const int r = tid & 31;
        float acc = b1[r] + part[tid][0] + part[tid][1]
                  + part[tid][2] + part[tid][3];
        float h = fmaxf(acc, 0.f);
        if (tid < 32) h1a[r] = h; else h1m[r] = h;
    }
    __syncthreads();
    for (int c = tid; c < NC; c += 256) {
        float acc = 2.f * b2[c];
        const float* wrow = w2 + c * NR;
        for (int r = 0; r < NR; ++r) acc += (h1a[r] + h1m[r]) * wrow[r];
        s_out[b * NC + c] = 1.f / (1.f + expf(-acc));
    }
}

// ---------------- Kernel 3: channel max/mean of x*s -> cp ----------------
__global__ __launch_bounds__(256) void spatial_pool_kernel(
        const float* __restrict__ x, const float* __restrict__ s,
        float* __restrict__ cp_max, float* __restrict__ cp_avg) {
    __shared__ float sc[NC];
    __shared__ float4 pmx[7][32];
    __shared__ float4 psm[7][32];
    const int b = blockIdx.y, tid = threadIdx.x;
    const int qo = tid & 31;                 // float4-pixel within tile
    const int cg = tid >> 5;                 // channel group 0..7
    const int q = blockIdx.x * 32 + qo;      // float4 index, 0..783 valid
    for (int c = tid; c < NC; c += 256) sc[c] = s[b * NC + c];
    __syncthreads();
    const float4* xb4 = (const float4*)(x + (size_t)b * NC * NHW);
    float4 mx = make_float4(-INFINITY, -INFINITY, -INFINITY, -INFINITY);
    float4 sm = make_float4(0.f, 0.f, 0.f, 0.f);
    const bool valid = (q < NHW / 4);
    if (valid) {
        #pragma unroll 2
        for (int c = cg * 64; c < cg * 64 + 64; ++c) {
            float4 v = xb4[(size_t)c * (NHW / 4) + q];
            const float scv = sc[c];
            v.x *= scv; v.y *= scv; v.z *= scv; v.w *= scv;
            mx.x = fmaxf(mx.x, v.x); mx.y = fmaxf(mx.y, v.y);
            mx.z = fmaxf(mx.z, v.z); mx.w = fmaxf(mx.w, v.w);
            sm.x += v.x; sm.y += v.y; sm.z += v.z; sm.w += v.w;
        }
    }
    if (cg > 0 && valid) { pmx[cg - 1][qo] = mx; psm[cg - 1][qo] = sm; }
    __syncthreads();
    if (cg == 0 && valid) {
        #pragma unroll
        for (int i = 0; i < 7; ++i) {
            const float4 m2 = pmx[i][qo];
            const float4 s2 = psm[i][qo];
            mx.x = fmaxf(mx.x, m2.x); mx.y = fmaxf(mx.y, m2.y);
            mx.z = fmaxf(mx.z, m2.z); mx.w = fmaxf(mx.w, m2.w);
            sm.x += s2.x; sm.y += s2.y; sm.z += s2.z; sm.w += s2.w;
        }
        const float inv = 1.0f / (float)NC;
        sm.x *= inv; sm.y *= inv; sm.z *= inv; sm.w *= inv;
        ((float4*)(cp_max + b * NHW))[q] = mx;
        ((float4*)(cp_avg + b * NHW))[q] = sm;
    }
}

// ---------------- Kernel 4: 7x7 conv + BN + sigmoid -> g[b,hw] -----------
__global__ __launch_bounds__(256) void conv_gate_kernel(
        const float* __restrict__ cp_max, const float* __restrict__ cp_avg,
        const float* __restrict__ conv_w,
        const float* __restrict__ gamma, const float* __restrict__ beta,
        const float* __restrict__ mean, const float* __restrict__ var,
        float* __restrict__ g) {
    __shared__ float wgt[98];
    const int b = blockIdx.y, tid = threadIdx.x;
    const int p = blockIdx.x * 256 + tid;
    if (tid < 98) wgt[tid] = conv_w[tid];
    __syncthreads();
    if (p >= NHW) return;
    const int h = p / NW, w = p - h * NW;
    const float* cm = cp_max + b * NHW;
    const float* ca = cp_avg + b * NHW;
    float acc = 0.f;
    for (int i = 0; i < 7; ++i) {
        const int hh = h - 3 + i;
        if (hh < 0 || hh >= NH) continue;
        for (int j = 0; j < 7; ++j) {
            const int ww = w - 3 + j;
            if (ww < 0 || ww >= NW) continue;
            const int q = hh * NW + ww;
            acc += cm[q] * wgt[i * 7 + j] + ca[q] * wgt[49 + i * 7 + j];
        }
    }
    const float bnv = (acc - mean[0]) * rsqrtf(var[0] + 1e-5f) * gamma[0] + beta[0];
    g[b * NHW + p] = 1.f / (1.f + expf(-bnv));
}

// ---------------- Kernel 5: out = x * s[b,c] * g[b,hw] -------------------
// One block per (b,c) row: scalar s broadcast, nontemporal stores so the
// 205 MB output stream doesn't evict x from L3.
__global__ __launch_bounds__(256) void scale_out_kernel(
        const float* __restrict__ x, const float* __restrict__ s,
        const float* __restrict__ g, float* __restrict__ out) {
    const int bc = blockIdx.x;               // 0..16383
    const int b = bc >> 9;
    const int tid = threadIdx.x;
    const float sv = s[bc];
    const f32x4* xr = (const f32x4*)(x + (size_t)bc * NHW);
    const f32x4* gr = (const f32x4*)(g + (size_t)b * NHW);
    f32x4* orow = (f32x4*)(out + (size_t)bc * NHW);
    #pragma unroll
    for (int i = 0; i < 3; ++i) {            // 3*256 = 768 of 784 float4s
        const int q = tid + 256 * i;
        f32x4 xv = xr[q];
        f32x4 gv = gr[q];
        f32x4 ov = xv * sv * gv;
        __builtin_nontemporal_store(ov, &orow[q]);
    }
    if (tid < 16) {                          // tail: 768..783
        const int q = 768 + tid;
        f32x4 xv = xr[q];
        f32x4 gv = gr[q];
        f32x4 ov = xv * sv * gv;
        __builtin_nontemporal_store(ov, &orow[q]);
    }
}

extern "C" void kernel_launch(void* const* d_in, const int* in_sizes, int n_in,
                              void* d_out, int out_size, void* d_ws, size_t ws_size,
                              hipStream_t stream) {
    const float* x      = (const float*)d_in[0];
    const float* w1     = (const float*)d_in[1];
    const float* b1     = (const float*)d_in[2];
    const float* w2     = (const float*)d_in[3];
    const float* b2     = (const float*)d_in[4];
    const float* conv_w = (const float*)d_in[5];
    const float* gamma  = (const float*)d_in[6];
    const float* beta   = (const float*)d_in[7];
    const float* mean   = (const float*)d_in[8];
    const float* var    = (const float*)d_in[9];
    float* out = (float*)d_out;

    float* ws = (float*)d_ws;
    float* pool_avg = ws;                       // 16384
    float* pool_max = ws + 16384;               // 16384
    float* s        = ws + 32768;               // 16384
    float* cp_max   = ws + 49152;               // 100352
    float* cp_avg   = ws + 149504;              // 100352
    float* g        = ws + 249856;              // 100352  (total 1.37 MB)

    topk_pool_kernel<<<NB * NC / 2, 256, 0, stream>>>(x, pool_avg, pool_max);
    mlp_kernel<<<NB, 256, 0, stream>>>(pool_avg, pool_max, w1, b1, w2, b2, s);
    dim3 grid3((NHW / 4 + 31) / 32, NB);        // (25, 32) = 800 blocks
    spatial_pool_kernel<<<grid3, 256, 0, stream>>>(x, s, cp_max, cp_avg);
    dim3 grid4((NHW + 255) / 256, NB);
    conv_gate_kernel<<<grid4, 256, 0, stream>>>(cp_max, cp_avg, conv_w,
                                                gamma, beta, mean, var, g);
    scale_out_kernel<<<NB * NC, 256, 0, stream>>>(x, s, g, out);
}